// Round 7
// baseline (292.373 us; speedup 1.0000x reference)
//
#include <hip/hip_runtime.h>
#include <cstdint>
#include <cstring>

#define M_TOK 2048   // BT*S
#define DDIM 4096
#define CDIM 1024
#define LTOT 25

typedef __bf16 bf16_t;
typedef __attribute__((ext_vector_type(8))) __bf16 bf16x8;
typedef __attribute__((ext_vector_type(4))) float f32x4;
typedef __attribute__((ext_vector_type(16))) float f32x16;

__device__ __forceinline__ void gload16(const void* g, void* l) {
  __builtin_amdgcn_global_load_lds(
      (const __attribute__((address_space(1))) unsigned int*)g,
      (__attribute__((address_space(3))) unsigned int*)l, 16, 0, 0);
}

// ---------------- fp32 -> bf16 convert ----------------
__global__ void cvt_bf16(const float* __restrict__ src, bf16_t* __restrict__ dst, long n) {
  long stride = (long)gridDim.x * blockDim.x;
  for (long i = (long)blockIdx.x * blockDim.x + threadIdx.x; i * 8 < n; i += stride) {
    const float4* s4 = (const float4*)(src + i * 8);
    float4 a = s4[0], b = s4[1];
    bf16_t o[8] = {(bf16_t)a.x, (bf16_t)a.y, (bf16_t)a.z, (bf16_t)a.w,
                   (bf16_t)b.x, (bf16_t)b.y, (bf16_t)b.z, (bf16_t)b.w};
    uint4 pk;
    __builtin_memcpy(&pk, o, 16);
    *(uint4*)(dst + i * 8) = pk;
  }
}

// ---------------- LayerNorm + gather + bf16 convert ----------------
// fuse7: when jl==0, also write the raw layer-24 row into slab 7 (fast path).
__global__ __launch_bounds__(256)
void ln_convert(const float* __restrict__ af, const float* __restrict__ gamma,
                const float* __restrict__ beta, bf16_t* __restrict__ xn,
                int jBase, int fuse7)
{
  int m = blockIdx.x;
  int jl = blockIdx.y;
  int j = jBase + jl;
  int layer = (j < 7) ? (24 - 4 * j) : 24;
  const float4* row4 = (const float4*)(af + ((size_t)m * LTOT + layer) * DDIM);
  int tid = threadIdx.x;
  float4 v[4];
  float s = 0.f, ss = 0.f;
#pragma unroll
  for (int i = 0; i < 4; ++i) {
    v[i] = row4[i * 256 + tid];
    s += v[i].x + v[i].y + v[i].z + v[i].w;
    ss += v[i].x * v[i].x + v[i].y * v[i].y + v[i].z * v[i].z + v[i].w * v[i].w;
  }
  int lane = tid & 63, wv = tid >> 6;
#pragma unroll
  for (int off = 32; off; off >>= 1) { s += __shfl_xor(s, off); ss += __shfl_xor(ss, off); }
  __shared__ float red[8];
  if (lane == 0) { red[wv] = s; red[4 + wv] = ss; }
  __syncthreads();
  s = red[0] + red[1] + red[2] + red[3];
  ss = red[4] + red[5] + red[6] + red[7];
  float mu = 0.f, rs = 1.f;
  if (j < 7) {
    mu = s * (1.f / DDIM);
    float var = ss * (1.f / DDIM) - mu * mu;
    rs = rsqrtf(var + 1e-5f);
  }
  // raw copy into slab 7 (fused with jl==0 which reads layer 24)
  if (fuse7 && jl == 0) {
    bf16_t* o7 = xn + ((size_t)7 * M_TOK + m) * DDIM;
#pragma unroll
    for (int i = 0; i < 4; ++i) {
      bf16_t o[4] = {(bf16_t)v[i].x, (bf16_t)v[i].y, (bf16_t)v[i].z, (bf16_t)v[i].w};
      uint2 pk;
      __builtin_memcpy(&pk, o, 8);
      ((uint2*)o7)[i * 256 + tid] = pk;
    }
  }
  bf16_t* orow = xn + ((size_t)jl * M_TOK + m) * DDIM;
  int jw = (j < 7) ? j : 0;
  const float4* g4 = (const float4*)(gamma + (size_t)jw * DDIM);
  const float4* b4 = (const float4*)(beta + (size_t)jw * DDIM);
#pragma unroll
  for (int i = 0; i < 4; ++i) {
    float4 x = v[i];
    float4 ov;
    if (j < 7) {
      float4 g = g4[i * 256 + tid], bb = b4[i * 256 + tid];
      ov.x = (x.x - mu) * rs * g.x + bb.x;
      ov.y = (x.y - mu) * rs * g.y + bb.y;
      ov.z = (x.z - mu) * rs * g.z + bb.z;
      ov.w = (x.w - mu) * rs * g.w + bb.w;
    } else ov = x;
    bf16_t o[4] = {(bf16_t)ov.x, (bf16_t)ov.y, (bf16_t)ov.z, (bf16_t)ov.w};
    uint2 pk;
    __builtin_memcpy(&pk, o, 8);
    ((uint2*)orow)[i * 256 + tid] = pk;
  }
}

// ---------------- 256x256-tile 8-phase batched B^T GEMM, 32x32x16 MFMA ----------
// C[jg][m][n] = bf16( sum_k A[jl][m][k] * B[jl][n][k] (+bias) )
// 512 threads = 8 waves (2 wm x 4 wn); per-wave output 128x64 = 4x2 blocks of 32.
// BK=64 (4 k-steps of 16). Staging/vmcnt ladder identical to round 6:
//   ph0: B0,B1(t+1)  ph1: B2,B3(t+1)  ph2: A1,A3(t+1)  ph3: A0,A2(t+2)
//   waits: ph1-end vmcnt(6), ph3-end vmcnt(4); tails 6/2 then 0/none.
// LDS storage: chunk-local row lr, stored slot d holds global k-slot d^(lr&7)
// (source pre-swizzle (lane&7)^((lane>>3)&7), linear gload dest).
// 32x32 frags: A row=lane&31, k=(lane>>5)*8+e -> read slot (ks*2+(lane>>5))^(lane&7).
// C/D: col=lane&31, row=(reg&3)+8*(reg>>2)+4*(lane>>5)   [m74/m101 verified]
__global__ __launch_bounds__(512, 2)
void gemm256(const bf16_t* __restrict__ A, const bf16_t* __restrict__ B,
             bf16_t* __restrict__ Cout, const float* __restrict__ bias,
             int Mm, int Nn, int Kk, int jBase, int tilesPerJ, int tilesN)
{
  __shared__ __align__(16) char smem[131072];  // [0,64K) A bufs, [64K,128K) B bufs
  int nb = gridDim.x;
  int bid = blockIdx.x;
  if ((nb & 7) == 0) { int cpx = nb >> 3; bid = (bid & 7) * cpx + (bid >> 3); }  // XCD swizzle
  int jl = bid / tilesPerJ;
  int t0 = bid % tilesPerJ;
  int bm = t0 / tilesN, bn = t0 % tilesN;
  int jg = jBase + jl;

  const bf16_t* Aj = A + (size_t)jl * Mm * Kk + (size_t)bm * 256 * Kk;
  const bf16_t* Bj = B + (size_t)jl * Nn * Kk + (size_t)bn * 256 * Kk;

  int tid = threadIdx.x;
  int lane = tid & 63, wid = tid >> 6;
  int wm = wid >> 2, wn = wid & 3;

  // staging source (per chunk c, tile tt): row = c*64 + wid*8 + (lane>>3),
  // k-slot pre-swizzle gslot = (lane&7)^((lane>>3)&7)
  const bf16_t* Ast = Aj + (size_t)(wid * 8 + (lane >> 3)) * Kk + ((lane & 7) ^ ((lane >> 3) & 7)) * 8;
  const bf16_t* Bst = Bj + (size_t)(wid * 8 + (lane >> 3)) * Kk + ((lane & 7) ^ ((lane >> 3) & 7)) * 8;

  // read addressing (32x32 frag): chunk-local row = blk*32 + (lane&31);
  // k-step ks byte slot = ((ks*2 + (lane>>5)) ^ (lane&7)) * 16
  int l31 = lane & 31;
  int lh = lane >> 5;           // k-half
  int l7 = lane & 7;
  int ksl[4];
#pragma unroll
  for (int ks = 0; ks < 4; ++ks) ksl[ks] = ((ks * 2 + lh) ^ l7) * 16;

  int NT = Kk >> 6;
  f32x16 acc[4][2] = {};        // [M-block 0..3][N-block 0..1]
  bf16x8 Af[2][4], Bf[2][4];    // [blk][ks]

#define STAGEA(c_, tt_)                                                          \
  gload16(Ast + (size_t)(c_) * 64 * Kk + (size_t)(tt_) * 64,                     \
          &smem[(((tt_) & 1) * 32768) + (c_) * 8192 + wid * 1024])
#define STAGEB(c_, tt_)                                                          \
  gload16(Bst + (size_t)(c_) * 64 * Kk + (size_t)(tt_) * 64,                     \
          &smem[65536 + (((tt_) & 1) * 32768) + (c_) * 8192 + wid * 1024])

  // A chunk for (wm, ih): c = wm*2 + ih; local rows im*32 + l31 (im=0..1)
#define LOADA(buf_, ih_)                                                         \
  { const char* Ac_ = &smem[(buf_) * 32768 + (wm * 2 + (ih_)) * 8192];           \
    _Pragma("unroll")                                                            \
    for (int im_ = 0; im_ < 2; ++im_)                                            \
      _Pragma("unroll")                                                          \
      for (int ks_ = 0; ks_ < 4; ++ks_)                                          \
        Af[im_][ks_] = *(const bf16x8*)(Ac_ + (im_ * 32 + l31) * 128 + ksl[ks_]); }

  // B chunk = wn; N-block jh: local rows jh*32 + l31
#define LOADB(buf_, jh_)                                                         \
  { const char* Bc_ = &smem[65536 + (buf_) * 32768 + wn * 8192];                 \
    _Pragma("unroll")                                                            \
    for (int ks_ = 0; ks_ < 4; ++ks_)                                            \
      Bf[jh_][ks_] = *(const bf16x8*)(Bc_ + ((jh_) * 32 + l31) * 128 + ksl[ks_]); }

#define MFMAQ(ih_, jh_)                                                          \
  { __builtin_amdgcn_s_setprio(1);                                               \
    _Pragma("unroll")                                                            \
    for (int im_ = 0; im_ < 2; ++im_)                                            \
      _Pragma("unroll")                                                          \
      for (int ks_ = 0; ks_ < 4; ++ks_)                                          \
        acc[(ih_) * 2 + im_][jh_] = __builtin_amdgcn_mfma_f32_32x32x16_bf16(     \
            Af[im_][ks_], Bf[jh_][ks_], acc[(ih_) * 2 + im_][jh_], 0, 0, 0);     \
    __builtin_amdgcn_s_setprio(0); }

#define BAR() asm volatile("s_barrier" ::: "memory")
#define LGKM0() asm volatile("s_waitcnt lgkmcnt(0)" ::: "memory")

  // prologue: tile 0 (8 loads) + A0,A2 of tile 1 = 10 in flight
  STAGEB(0, 0); STAGEB(1, 0); STAGEB(2, 0); STAGEB(3, 0);
  STAGEA(0, 0); STAGEA(2, 0); STAGEA(1, 0); STAGEA(3, 0);
  if (NT > 1) { STAGEA(0, 1); STAGEA(2, 1); }
  asm volatile("s_waitcnt vmcnt(4)" ::: "memory");  // tile-0 B*,A0,A2 landed
  BAR();

#pragma unroll 1
  for (int t = 0; t < NT; ++t) {
    int buf = t & 1;
    // ---- phase 0: quadrant (0,0); stage B0,B1(t+1) ----
    LOADA(buf, 0);
    LOADB(buf, 0);
    if (t + 1 < NT) { STAGEB(0, t + 1); STAGEB(1, t + 1); }
    BAR(); LGKM0();
    MFMAQ(0, 0);
    BAR();
    // ---- phase 1: quadrant (0,1); stage B2,B3(t+1); wait A1,A3(t) drained ----
    LOADB(buf, 1);
    if (t + 1 < NT) { STAGEB(2, t + 1); STAGEB(3, t + 1); }
    BAR(); LGKM0();
    MFMAQ(0, 1);
    if (t + 1 < NT) asm volatile("s_waitcnt vmcnt(6)" ::: "memory");
    else            asm volatile("s_waitcnt vmcnt(0)" ::: "memory");
    BAR();
    // ---- phase 2: quadrant (1,0); stage A1,A3(t+1) ----
    LOADA(buf, 1);
    if (t + 1 < NT) { STAGEA(1, t + 1); STAGEA(3, t + 1); }
    BAR(); LGKM0();
    MFMAQ(1, 0);
    BAR();
    // ---- phase 3: quadrant (1,1); stage A0,A2(t+2); wait t+1 B*,A0,A2 ----
    if (t + 2 < NT) { STAGEA(0, t + 2); STAGEA(2, t + 2); }
    BAR(); LGKM0();
    MFMAQ(1, 1);
    if (t + 2 < NT)      asm volatile("s_waitcnt vmcnt(4)" ::: "memory");
    else if (t + 1 < NT) asm volatile("s_waitcnt vmcnt(2)" ::: "memory");
    BAR();
  }
#undef STAGEA
#undef STAGEB
#undef LOADA
#undef LOADB
#undef MFMAQ
#undef BAR
#undef LGKM0

  // epilogue: C/D col=lane&31, row=(reg&3)+8*(reg>>2)+4*(lane>>5)
  int col0 = bn * 256 + wn * 64 + l31;
  int row0 = bm * 256 + wm * 128 + lh * 4;
  bf16_t* Cj = Cout + (size_t)jg * Mm * Nn;
  float bv0 = (jg == 7) ? bias[col0] : 0.f;
  float bv1 = (jg == 7) ? bias[col0 + 32] : 0.f;
#pragma unroll
  for (int im = 0; im < 4; ++im) {
#pragma unroll
    for (int jn = 0; jn < 2; ++jn) {
      float bv = jn ? bv1 : bv0;
      int gc = col0 + jn * 32;
#pragma unroll
      for (int reg = 0; reg < 16; ++reg) {
        int gr = row0 + im * 32 + (reg & 3) + 8 * (reg >> 2);
        Cj[(size_t)gr * Nn + gc] = (bf16_t)(acc[im][jn][reg] + bv);
      }
    }
  }
}

// ---------------- 128x128-tile GEMM for the output projection ----------------
// C[m][n] = sum_k A[m][k]*B[n][k] + bias[n] + vin[m][n]   (vin bf16)
__global__ __launch_bounds__(256)
void gemm_bt_epi(const bf16_t* __restrict__ A, const bf16_t* __restrict__ B,
                 float* __restrict__ Cout, const float* __restrict__ bias,
                 const bf16_t* __restrict__ vin, int Mm, int Nn, int Kk, int tilesN)
{
  __shared__ bf16_t As[128 * 64];
  __shared__ bf16_t Bs[128 * 64];
  int bid = blockIdx.x;
  int bm = bid / tilesN, bn = bid % tilesN;
  const bf16_t* Aj = A + (size_t)bm * 128 * Kk;
  const bf16_t* Bj = B + (size_t)bn * 128 * Kk;

  int tid = threadIdx.x;
  int lane = tid & 63, wv = tid >> 6;
  int wm = wv >> 1, wn = wv & 1;

  f32x4 acc[4][4] = {};

  int srow = wv * 32 + (lane >> 3);
  int scol = (lane & 7) * 8;
  const bf16_t* Ag = Aj + (size_t)srow * Kk + scol;
  const bf16_t* Bg = Bj + (size_t)srow * Kk + scol;

  for (int kt = 0; kt < Kk; kt += 64) {
#pragma unroll
    for (int c = 0; c < 4; ++c) {
      gload16(Ag + kt + (size_t)(c * 8) * Kk, &As[(wv * 32 + c * 8) * 64]);
      gload16(Bg + kt + (size_t)(c * 8) * Kk, &Bs[(wv * 32 + c * 8) * 64]);
    }
    __syncthreads();
#pragma unroll
    for (int ks = 0; ks < 2; ++ks) {
      int ko = ks * 32 + (lane >> 4) * 8;
      bf16x8 af[4], bfr[4];
#pragma unroll
      for (int i = 0; i < 4; ++i) {
        af[i] = *(const bf16x8*)&As[(wm * 64 + i * 16 + (lane & 15)) * 64 + ko];
        bfr[i] = *(const bf16x8*)&Bs[(wn * 64 + i * 16 + (lane & 15)) * 64 + ko];
      }
#pragma unroll
      for (int i = 0; i < 4; ++i)
#pragma unroll
        for (int j2 = 0; j2 < 4; ++j2)
          acc[i][j2] = __builtin_amdgcn_mfma_f32_16x16x32_bf16(af[i], bfr[j2], acc[i][j2], 0, 0, 0);
    }
    __syncthreads();
  }

  int rowBase = bm * 128 + wm * 64 + (lane >> 4) * 4;
  int colBase = bn * 128 + wn * 64 + (lane & 15);
#pragma unroll
  for (int i = 0; i < 4; ++i) {
#pragma unroll
    for (int j2 = 0; j2 < 4; ++j2) {
      int gn = colBase + j2 * 16;
      float bv = bias[gn];
#pragma unroll
      for (int r = 0; r < 4; ++r) {
        int gm = rowBase + i * 16 + r;
        Cout[(size_t)gm * Nn + gn] = acc[i][j2][r] + bv + (float)vin[(size_t)gm * Nn + gn];
      }
    }
  }
}

// ---------------- attention over 6 kv slabs (vo bf16) ----------------
__global__ __launch_bounds__(512)
void attn_fuse(const bf16_t* __restrict__ vo, bf16_t* __restrict__ fuse)
{
  int m = blockIdx.x;
  int h = threadIdx.x >> 6;
  int lane = threadIdx.x & 63;
  const size_t slab = (size_t)M_TOK * CDIM;
  const bf16_t* base = vo + (size_t)m * CDIM + h * 128;
  float q0 = (float)base[lane], q1 = (float)base[lane + 64];
  float kv0[6], kv1[6], sc[6];
#pragma unroll
  for (int k = 0; k < 6; ++k) {
    const bf16_t* kb = base + (size_t)(k + 1) * slab;
    kv0[k] = (float)kb[lane]; kv1[k] = (float)kb[lane + 64];
    sc[k] = q0 * kv0[k] + q1 * kv1[k];
  }
#pragma unroll
  for (int k = 0; k < 6; ++k) {
#pragma unroll
    for (int off = 32; off; off >>= 1) sc[k] += __shfl_xor(sc[k], off);
    sc[k] *= 0.03125f;  // C^-0.5
  }
  float mx = sc[0];
#pragma unroll
  for (int k = 1; k < 6; ++k) mx = fmaxf(mx, sc[k]);
  float e[6], se = 0.f;
#pragma unroll
  for (int k = 0; k < 6; ++k) { e[k] = expf(sc[k] - mx); se += e[k]; }
  float inv = 1.f / se;
  float f0 = 0.f, f1 = 0.f;
#pragma unroll
  for (int k = 0; k < 6; ++k) { float w = e[k] * inv; f0 += w * kv0[k]; f1 += w * kv1[k]; }
  bf16_t* o = fuse + (size_t)m * CDIM + h * 128;
  o[lane] = (bf16_t)f0;
  o[lane + 64] = (bf16_t)f1;
}

// ---------------- cosine per row ----------------
__global__ __launch_bounds__(256)
void cos_row(const float* __restrict__ vf, const float* __restrict__ teacher, float* __restrict__ cosv)
{
  int m = blockIdx.x;
  int tid = threadIdx.x;
  float4 a = ((const float4*)(vf + (size_t)m * CDIM))[tid];
  float4 b = ((const float4*)(teacher + (size_t)m * CDIM))[tid];
  float dot = a.x * b.x + a.y * b.y + a.z * b.z + a.w * b.w;
  float na = a.x * a.x + a.y * a.y + a.z * a.z + a.w * a.w;
  float nb = b.x * b.x + b.y * b.y + b.z * b.z + b.w * b.w;
  int lane = tid & 63, wv = tid >> 6;
#pragma unroll
  for (int off = 32; off; off >>= 1) {
    dot += __shfl_xor(dot, off); na += __shfl_xor(na, off); nb += __shfl_xor(nb, off);
  }
  __shared__ float red[12];
  if (lane == 0) { red[wv] = dot; red[4 + wv] = na; red[8 + wv] = nb; }
  __syncthreads();
  if (tid == 0) {
    float d = red[0] + red[1] + red[2] + red[3];
    float x = red[4] + red[5] + red[6] + red[7];
    float y = red[8] + red[9] + red[10] + red[11];
    float den = fmaxf(sqrtf(x), 1e-8f) * fmaxf(sqrtf(y), 1e-8f);
    cosv[m] = d / den;
  }
}

__global__ __launch_bounds__(256)
void final_reduce(const float* __restrict__ cosv, float* __restrict__ out)
{
  int tid = threadIdx.x;
  float s = 0.f;
  for (int i = tid; i < M_TOK; i += 256) s += cosv[i];
  int lane = tid & 63, wv = tid >> 6;
#pragma unroll
  for (int off = 32; off; off >>= 1) s += __shfl_xor(s, off);
  __shared__ float red[4];
  if (lane == 0) red[wv] = s;
  __syncthreads();
  if (tid == 0) out[0] = 1.f - (red[0] + red[1] + red[2] + red[3]) * (1.f / M_TOK);
}

extern "C" void kernel_launch(void* const* d_in, const int* in_sizes, int n_in,
                              void* d_out, int out_size, void* d_ws, size_t ws_size,
                              hipStream_t stream)
{
  (void)in_sizes; (void)n_in; (void)out_size;
  const float* all_features = (const float*)d_in[0];
  const float* teacher = (const float*)d_in[1];
  const float* ln_gamma = (const float*)d_in[2];
  const float* ln_beta = (const float*)d_in[3];
  const float* norm_w = (const float*)d_in[4];
  const float* input_w = (const float*)d_in[5];
  const float* input_b = (const float*)d_in[6];
  const float* output_w = (const float*)d_in[7];
  const float* output_b = (const float*)d_in[8];
  float* out = (float*)d_out;
  char* ws = (char*)d_ws;

  const size_t M = M_TOK, D = DDIM, C = CDIM;
  const size_t xnB = 8 * M * D * 2;      // 134 MB
  const size_t wbB = 8 * C * D * 2;      // 67 MB
  const size_t owbB = C * C * 2;         // 2 MB
  const size_t voB = 8 * M * C * 2;      // 33.5 MB (bf16; slab7 = vin)
  const size_t fuseB = M * C * 2;
  const size_t vfB = M * C * 4;
  const size_t cosB = M * 4;
  const size_t fastTotal = xnB + wbB + owbB + voB + fuseB + vfB + cosB;

  if (ws_size >= fastTotal) {
    bf16_t* xn = (bf16_t*)ws;
    bf16_t* wb = (bf16_t*)(ws + xnB);
    bf16_t* owb = (bf16_t*)(ws + xnB + wbB);
    bf16_t* vo = (bf16_t*)(ws + xnB + wbB + owbB);
    bf16_t* fuse = (bf16_t*)(ws + xnB + wbB + owbB + voB);
    float* vf = (float*)(ws + xnB + wbB + owbB + voB + fuseB);
    float* cosv = (float*)(ws + xnB + wbB + owbB + voB + fuseB + vfB);

    cvt_bf16<<<4096, 256, 0, stream>>>(norm_w, wb, (long)7 * C * D);
    cvt_bf16<<<2048, 256, 0, stream>>>(input_w, wb + (size_t)7 * C * D, (long)(C * D));
    cvt_bf16<<<512, 256, 0, stream>>>(output_w, owb, (long)(C * C));
    dim3 g1((unsigned)M, 7);
    ln_convert<<<g1, 256, 0, stream>>>(all_features, ln_gamma, ln_beta, xn, 0, 1);
    gemm256<<<256, 512, 0, stream>>>(xn, wb, vo, input_b,
                                     (int)M, (int)C, (int)D, 0, 32, 4);
    attn_fuse<<<(unsigned)M, 512, 0, stream>>>(vo, fuse);
    gemm_bt_epi<<<128, 256, 0, stream>>>(fuse, owb, vf, output_b, vo + (size_t)7 * M * C,
                                         (int)M, (int)C, (int)C, 8);
    cos_row<<<(unsigned)M, 256, 0, stream>>>(vf, teacher, cosv);
    final_reduce<<<1, 256, 0, stream>>>(cosv, out);
  } else {
    // SMALL-ws fallback: loop j, reuse one xn/wb slab.
    const size_t xn1B = M * D * 2;
    const size_t wb1B = C * D * 2;
    bf16_t* xn1 = (bf16_t*)ws;
    bf16_t* wb1 = (bf16_t*)(ws + xn1B);
    bf16_t* owb = (bf16_t*)(ws + xn1B + wb1B);
    bf16_t* vo = (bf16_t*)(ws + xn1B + wb1B + owbB);
    bf16_t* fuse = (bf16_t*)(ws + xn1B + wb1B + owbB + voB);
    float* vf = (float*)(ws + xn1B + wb1B + owbB + voB + fuseB);
    float* cosv = (float*)(ws + xn1B + wb1B + owbB + voB + fuseB + vfB);

    cvt_bf16<<<512, 256, 0, stream>>>(output_w, owb, (long)(C * C));
    for (int j = 0; j < 8; ++j) {
      const float* wsrc = (j < 7) ? (norm_w + (size_t)j * C * D) : input_w;
      cvt_bf16<<<2048, 256, 0, stream>>>(wsrc, wb1, (long)(C * D));
      dim3 g1((unsigned)M, 1);
      ln_convert<<<g1, 256, 0, stream>>>(all_features, ln_gamma, ln_beta, xn1, j, 0);
      gemm256<<<32, 512, 0, stream>>>(xn1, wb1, vo, input_b,
                                      (int)M, (int)C, (int)D, j, 32, 4);
    }
    attn_fuse<<<(unsigned)M, 512, 0, stream>>>(vo, fuse);
    gemm_bt_epi<<<128, 256, 0, stream>>>(fuse, owb, vf, output_b, vo + (size_t)7 * M * C,
                                         (int)M, (int)C, (int)C, 8);
    cos_row<<<(unsigned)M, 256, 0, stream>>>(vf, teacher, cosv);
    final_reduce<<<1, 256, 0, stream>>>(cosv, out);
  }
}

// Round 8
// 291.377 us; speedup vs baseline: 1.0034x; 1.0034x over previous
//
#include <hip/hip_runtime.h>
#include <cstdint>
#include <cstring>

#define M_TOK 2048   // BT*S
#define DDIM 4096
#define CDIM 1024
#define LTOT 25

typedef __bf16 bf16_t;
typedef __attribute__((ext_vector_type(8))) __bf16 bf16x8;
typedef __attribute__((ext_vector_type(4))) float f32x4;

__device__ __forceinline__ void gload16(const void* g, void* l) {
  __builtin_amdgcn_global_load_lds(
      (const __attribute__((address_space(1))) unsigned int*)g,
      (__attribute__((address_space(3))) unsigned int*)l, 16, 0, 0);
}

// ---------------- fp32 -> bf16 convert ----------------
__global__ void cvt_bf16(const float* __restrict__ src, bf16_t* __restrict__ dst, long n) {
  long stride = (long)gridDim.x * blockDim.x;
  for (long i = (long)blockIdx.x * blockDim.x + threadIdx.x; i * 8 < n; i += stride) {
    const float4* s4 = (const float4*)(src + i * 8);
    float4 a = s4[0], b = s4[1];
    bf16_t o[8] = {(bf16_t)a.x, (bf16_t)a.y, (bf16_t)a.z, (bf16_t)a.w,
                   (bf16_t)b.x, (bf16_t)b.y, (bf16_t)b.z, (bf16_t)b.w};
    uint4 pk;
    __builtin_memcpy(&pk, o, 16);
    *(uint4*)(dst + i * 8) = pk;
  }
}

// ---------------- LayerNorm + gather + bf16 convert ----------------
// fuse7: when jl==0, also write the raw layer-24 row into slab 7 (fast path).
__global__ __launch_bounds__(256)
void ln_convert(const float* __restrict__ af, const float* __restrict__ gamma,
                const float* __restrict__ beta, bf16_t* __restrict__ xn,
                int jBase, int fuse7)
{
  int m = blockIdx.x;
  int jl = blockIdx.y;
  int j = jBase + jl;
  int layer = (j < 7) ? (24 - 4 * j) : 24;
  const float4* row4 = (const float4*)(af + ((size_t)m * LTOT + layer) * DDIM);
  int tid = threadIdx.x;
  float4 v[4];
  float s = 0.f, ss = 0.f;
#pragma unroll
  for (int i = 0; i < 4; ++i) {
    v[i] = row4[i * 256 + tid];
    s += v[i].x + v[i].y + v[i].z + v[i].w;
    ss += v[i].x * v[i].x + v[i].y * v[i].y + v[i].z * v[i].z + v[i].w * v[i].w;
  }
  int lane = tid & 63, wv = tid >> 6;
#pragma unroll
  for (int off = 32; off; off >>= 1) { s += __shfl_xor(s, off); ss += __shfl_xor(ss, off); }
  __shared__ float red[8];
  if (lane == 0) { red[wv] = s; red[4 + wv] = ss; }
  __syncthreads();
  s = red[0] + red[1] + red[2] + red[3];
  ss = red[4] + red[5] + red[6] + red[7];
  float mu = 0.f, rs = 1.f;
  if (j < 7) {
    mu = s * (1.f / DDIM);
    float var = ss * (1.f / DDIM) - mu * mu;
    rs = rsqrtf(var + 1e-5f);
  }
  // raw copy into slab 7 (fused with jl==0 which reads layer 24)
  if (fuse7 && jl == 0) {
    bf16_t* o7 = xn + ((size_t)7 * M_TOK + m) * DDIM;
#pragma unroll
    for (int i = 0; i < 4; ++i) {
      bf16_t o[4] = {(bf16_t)v[i].x, (bf16_t)v[i].y, (bf16_t)v[i].z, (bf16_t)v[i].w};
      uint2 pk;
      __builtin_memcpy(&pk, o, 8);
      ((uint2*)o7)[i * 256 + tid] = pk;
    }
  }
  bf16_t* orow = xn + ((size_t)jl * M_TOK + m) * DDIM;
  int jw = (j < 7) ? j : 0;
  const float4* g4 = (const float4*)(gamma + (size_t)jw * DDIM);
  const float4* b4 = (const float4*)(beta + (size_t)jw * DDIM);
#pragma unroll
  for (int i = 0; i < 4; ++i) {
    float4 x = v[i];
    float4 ov;
    if (j < 7) {
      float4 g = g4[i * 256 + tid], bb = b4[i * 256 + tid];
      ov.x = (x.x - mu) * rs * g.x + bb.x;
      ov.y = (x.y - mu) * rs * g.y + bb.y;
      ov.z = (x.z - mu) * rs * g.z + bb.z;
      ov.w = (x.w - mu) * rs * g.w + bb.w;
    } else ov = x;
    bf16_t o[4] = {(bf16_t)ov.x, (bf16_t)ov.y, (bf16_t)ov.z, (bf16_t)ov.w};
    uint2 pk;
    __builtin_memcpy(&pk, o, 8);
    ((uint2*)orow)[i * 256 + tid] = pk;
  }
}

// ------- 256x256-tile batched B^T GEMM: BK=32, ring-4 LDS, pipelined windows ------
// C[jg][m][n] = bf16( sum_k A[jl][m][k] * B[jl][n][k] (+bias) )
// 512 threads = 8 waves (2 wm x 4 wn); per-wave output 128x64. 16x16x32 MFMA.
// Ring: 4 bufs x (A 256x32 + B 256x32) = 128 KB. Per tile: 2 windows.
//   even(t): dsread AfE(t)[4]+Bf(t)[4] | stage A(t+2) | MFMA ip4-7(t-1) | BAR
//   odd(t):  dsread AfO(t)[4]          | stage B(t+2) | MFMA ip0-3(t)  | vmcnt(4) | BAR
// Frags read one window before their MFMA -> compiler's counted lgkm waits let
// the current window's reads stream under the MFMA cluster. 16 indep acc chains.
// vmcnt(4) at odd-end leaves exactly {A,B}(t+2) outstanding; waited loads have
// 3-4 windows slack. Swizzle: stored slot d of row r holds k-slot d^((r>>1)&3);
// source pre-swz (l&3)^((l>>3)&3); read slot (lane>>4)^((lane>>1)&3). 2-way=free.
__global__ __launch_bounds__(512, 2)
void gemm256(const bf16_t* __restrict__ A, const bf16_t* __restrict__ B,
             bf16_t* __restrict__ Cout, const float* __restrict__ bias,
             int Mm, int Nn, int Kk, int jBase, int tilesPerJ, int tilesN)
{
  __shared__ __align__(16) char smem[131072];  // [0,64K) A ring, [64K,128K) B ring
  int nb = gridDim.x;
  int bid = blockIdx.x;
  if ((nb & 7) == 0) { int cpx = nb >> 3; bid = (bid & 7) * cpx + (bid >> 3); }  // XCD swizzle
  int jl = bid / tilesPerJ;
  int t0 = bid % tilesPerJ;
  int bm = t0 / tilesN, bn = t0 % tilesN;
  int jg = jBase + jl;

  const bf16_t* Aj = A + (size_t)jl * Mm * Kk + (size_t)bm * 256 * Kk;
  const bf16_t* Bj = B + (size_t)jl * Nn * Kk + (size_t)bn * 256 * Kk;

  int tid = threadIdx.x;
  int lane = tid & 63, wid = tid >> 6;
  int wm = wid >> 2, wn = wid & 3;
  int rb = lane & 15;
  int sp = ((lane >> 4) ^ ((lane >> 1) & 3)) * 16;   // read byte-slot in 64B row

  // staging: chunk c covers tile rows c*128..c*128+127; wave writes rows wid*16+(l>>2)
  int srow = wid * 16 + (lane >> 2);
  int pre = ((lane & 3) ^ ((lane >> 3) & 3)) * 8;    // source k-slot pre-swizzle
  const bf16_t* AstC[2] = { Aj + (size_t)srow * Kk + pre,
                            Aj + (size_t)(128 + srow) * Kk + pre };
  const bf16_t* BstC[2] = { Bj + (size_t)srow * Kk + pre,
                            Bj + (size_t)(128 + srow) * Kk + pre };

  // read bases: A chunk = wm (rows ip*16+rb; AfO at +4096 = rows 64..127)
  //             B chunk = wn>>1, sub-half (wn&1)*4096
  const char* AbR = &smem[wm * 8192];
  const char* BbR = &smem[65536 + (wn >> 1) * 8192 + (wn & 1) * 4096];

  int NT = Kk >> 5;                                  // 32-K tiles (even, >=32)
  f32x4 acc[8][4] = {};
  bf16x8 AfE[4], AfO[4], BfA[4], BfB[4];

#define STA(c_, tt_) gload16(AstC[c_] + (size_t)(tt_) * 32,                      \
    &smem[((tt_) & 3) * 16384 + (c_) * 8192 + wid * 1024])
#define STB(c_, tt_) gload16(BstC[c_] + (size_t)(tt_) * 32,                      \
    &smem[65536 + ((tt_) & 3) * 16384 + (c_) * 8192 + wid * 1024])
#define RD_E(T_, BC_) { const char* a_ = AbR + ((T_) & 3) * 16384;               \
    const char* b_ = BbR + ((T_) & 3) * 16384;                                   \
    _Pragma("unroll") for (int i_ = 0; i_ < 4; ++i_)                             \
      AfE[i_] = *(const bf16x8*)(a_ + (i_ * 16 + rb) * 64 + sp);                 \
    _Pragma("unroll") for (int j_ = 0; j_ < 4; ++j_)                             \
      BC_[j_] = *(const bf16x8*)(b_ + (j_ * 16 + rb) * 64 + sp); }
#define RD_O(T_) { const char* a_ = AbR + ((T_) & 3) * 16384 + 4096;             \
    _Pragma("unroll") for (int i_ = 0; i_ < 4; ++i_)                             \
      AfO[i_] = *(const bf16x8*)(a_ + (i_ * 16 + rb) * 64 + sp); }
#define MM_LO(BC_) { __builtin_amdgcn_s_setprio(1);                              \
    _Pragma("unroll") for (int i_ = 0; i_ < 4; ++i_)                             \
      _Pragma("unroll") for (int j_ = 0; j_ < 4; ++j_)                           \
        acc[i_][j_] = __builtin_amdgcn_mfma_f32_16x16x32_bf16(                   \
            AfE[i_], BC_[j_], acc[i_][j_], 0, 0, 0);                             \
    __builtin_amdgcn_s_setprio(0); }
#define MM_HI(BC_) { __builtin_amdgcn_s_setprio(1);                              \
    _Pragma("unroll") for (int i_ = 0; i_ < 4; ++i_)                             \
      _Pragma("unroll") for (int j_ = 0; j_ < 4; ++j_)                           \
        acc[4 + i_][j_] = __builtin_amdgcn_mfma_f32_16x16x32_bf16(               \
            AfO[i_], BC_[j_], acc[4 + i_][j_], 0, 0, 0);                         \
    __builtin_amdgcn_s_setprio(0); }
#define BAR() asm volatile("s_barrier" ::: "memory")

  // prologue: stage tiles 0,1; wait tile 0; pre-read AfE(0),Bf(0)
  STA(0, 0); STA(1, 0); STB(0, 0); STB(1, 0);
  STA(0, 1); STA(1, 1); STB(0, 1); STB(1, 1);
  asm volatile("s_waitcnt vmcnt(4)" ::: "memory");
  BAR();
  RD_E(0, BfA);
  // peeled tile 0
  STA(0, 2); STA(1, 2);            // NT >= 32 always
  BAR();
  RD_O(0);
  STB(0, 2); STB(1, 2);
  MM_LO(BfA);
  asm volatile("s_waitcnt vmcnt(4)" ::: "memory");   // tile 1 landed
  BAR();
  // peeled tile 1
  RD_E(1, BfB);
  STA(0, 3); STA(1, 3);
  MM_HI(BfA);
  BAR();
  RD_O(1);
  STB(0, 3); STB(1, 3);
  MM_LO(BfB);
  asm volatile("s_waitcnt vmcnt(4)" ::: "memory");   // tile 2 landed
  BAR();

#pragma unroll 1
  for (int t = 2; t < NT; t += 2) {
    // tile t (even parity -> BfA)
    RD_E(t, BfA);
    if (t + 2 < NT) { STA(0, t + 2); STA(1, t + 2); }
    MM_HI(BfB);
    BAR();
    RD_O(t);
    if (t + 2 < NT) { STB(0, t + 2); STB(1, t + 2); }
    MM_LO(BfA);
    if (t + 2 < NT) asm volatile("s_waitcnt vmcnt(4)" ::: "memory");
    else            asm volatile("s_waitcnt vmcnt(0)" ::: "memory");
    BAR();
    // tile t+1 (odd parity -> BfB)
    RD_E(t + 1, BfB);
    if (t + 3 < NT) { STA(0, t + 3); STA(1, t + 3); }
    MM_HI(BfA);
    BAR();
    RD_O(t + 1);
    if (t + 3 < NT) { STB(0, t + 3); STB(1, t + 3); }
    MM_LO(BfB);
    if (t + 3 < NT)      asm volatile("s_waitcnt vmcnt(4)" ::: "memory");
    else if (t + 2 < NT) asm volatile("s_waitcnt vmcnt(0)" ::: "memory");
    BAR();
  }
  // drain: ip4-7 of tile NT-1 (odd parity)
  MM_HI(BfB);
#undef STA
#undef STB
#undef RD_E
#undef RD_O
#undef MM_LO
#undef MM_HI
#undef BAR

  int rowBase = bm * 256 + wm * 128 + (lane >> 4) * 4;
  int colBase = bn * 256 + wn * 64 + (lane & 15);
  bf16_t* Cj = Cout + (size_t)jg * Mm * Nn;
#pragma unroll
  for (int i = 0; i < 8; ++i) {
#pragma unroll
    for (int j = 0; j < 4; ++j) {
      int gn = colBase + j * 16;
      float bv = (jg == 7) ? bias[gn] : 0.f;
#pragma unroll
      for (int r = 0; r < 4; ++r) {
        int gm = rowBase + i * 16 + r;
        Cj[(size_t)gm * Nn + gn] = (bf16_t)(acc[i][j][r] + bv);
      }
    }
  }
}

// ---------------- 128x128-tile GEMM for the output projection ----------------
// C[m][n] = sum_k A[m][k]*B[n][k] + bias[n] + vin[m][n]   (vin bf16)
__global__ __launch_bounds__(256)
void gemm_bt_epi(const bf16_t* __restrict__ A, const bf16_t* __restrict__ B,
                 float* __restrict__ Cout, const float* __restrict__ bias,
                 const bf16_t* __restrict__ vin, int Mm, int Nn, int Kk, int tilesN)
{
  __shared__ bf16_t As[128 * 64];
  __shared__ bf16_t Bs[128 * 64];
  int bid = blockIdx.x;
  int bm = bid / tilesN, bn = bid % tilesN;
  const bf16_t* Aj = A + (size_t)bm * 128 * Kk;
  const bf16_t* Bj = B + (size_t)bn * 128 * Kk;

  int tid = threadIdx.x;
  int lane = tid & 63, wv = tid >> 6;
  int wm = wv >> 1, wn = wv & 1;

  f32x4 acc[4][4] = {};

  int srow = wv * 32 + (lane >> 3);
  int scol = (lane & 7) * 8;
  const bf16_t* Ag = Aj + (size_t)srow * Kk + scol;
  const bf16_t* Bg = Bj + (size_t)srow * Kk + scol;

  for (int kt = 0; kt < Kk; kt += 64) {
#pragma unroll
    for (int c = 0; c < 4; ++c) {
      gload16(Ag + kt + (size_t)(c * 8) * Kk, &As[(wv * 32 + c * 8) * 64]);
      gload16(Bg + kt + (size_t)(c * 8) * Kk, &Bs[(wv * 32 + c * 8) * 64]);
    }
    __syncthreads();
#pragma unroll
    for (int ks = 0; ks < 2; ++ks) {
      int ko = ks * 32 + (lane >> 4) * 8;
      bf16x8 af[4], bfr[4];
#pragma unroll
      for (int i = 0; i < 4; ++i) {
        af[i] = *(const bf16x8*)&As[(wm * 64 + i * 16 + (lane & 15)) * 64 + ko];
        bfr[i] = *(const bf16x8*)&Bs[(wn * 64 + i * 16 + (lane & 15)) * 64 + ko];
      }
#pragma unroll
      for (int i = 0; i < 4; ++i)
#pragma unroll
        for (int j2 = 0; j2 < 4; ++j2)
          acc[i][j2] = __builtin_amdgcn_mfma_f32_16x16x32_bf16(af[i], bfr[j2], acc[i][j2], 0, 0, 0);
    }
    __syncthreads();
  }

  int rowBase = bm * 128 + wm * 64 + (lane >> 4) * 4;
  int colBase = bn * 128 + wn * 64 + (lane & 15);
#pragma unroll
  for (int i = 0; i < 4; ++i) {
#pragma unroll
    for (int j2 = 0; j2 < 4; ++j2) {
      int gn = colBase + j2 * 16;
      float bv = bias[gn];
#pragma unroll
      for (int r = 0; r < 4; ++r) {
        int gm = rowBase + i * 16 + r;
        Cout[(size_t)gm * Nn + gn] = acc[i][j2][r] + bv + (float)vin[(size_t)gm * Nn + gn];
      }
    }
  }
}

// ---------------- attention over 6 kv slabs (vo bf16) ----------------
__global__ __launch_bounds__(512)
void attn_fuse(const bf16_t* __restrict__ vo, bf16_t* __restrict__ fuse)
{
  int m = blockIdx.x;
  int h = threadIdx.x >> 6;
  int lane = threadIdx.x & 63;
  const size_t slab = (size_t)M_TOK * CDIM;
  const bf16_t* base = vo + (size_t)m * CDIM + h * 128;
  float q0 = (float)base[lane], q1 = (float)base[lane + 64];
  float kv0[6], kv1[6], sc[6];
#pragma unroll
  for (int k = 0; k < 6; ++k) {
    const bf16_t* kb = base + (size_t)(k + 1) * slab;
    kv0[k] = (float)kb[lane]; kv1[k] = (float)kb[lane + 64];
    sc[k] = q0 * kv0[k] + q1 * kv1[k];
  }
#pragma unroll
  for (int k = 0; k < 6; ++k) {
#pragma unroll
    for (int off = 32; off; off >>= 1) sc[k] += __shfl_xor(sc[k], off);
    sc[k] *= 0.03125f;  // C^-0.5
  }
  float mx = sc[0];
#pragma unroll
  for (int k = 1; k < 6; ++k) mx = fmaxf(mx, sc[k]);
  float e[6], se = 0.f;
#pragma unroll
  for (int k = 0; k < 6; ++k) { e[k] = expf(sc[k] - mx); se += e[k]; }
  float inv = 1.f / se;
  float f0 = 0.f, f1 = 0.f;
#pragma unroll
  for (int k = 0; k < 6; ++k) { float w = e[k] * inv; f0 += w * kv0[k]; f1 += w * kv1[k]; }
  bf16_t* o = fuse + (size_t)m * CDIM + h * 128;
  o[lane] = (bf16_t)f0;
  o[lane + 64] = (bf16_t)f1;
}

// ---------------- cosine per row ----------------
__global__ __launch_bounds__(256)
void cos_row(const float* __restrict__ vf, const float* __restrict__ teacher, float* __restrict__ cosv)
{
  int m = blockIdx.x;
  int tid = threadIdx.x;
  float4 a = ((const float4*)(vf + (size_t)m * CDIM))[tid];
  float4 b = ((const float4*)(teacher + (size_t)m * CDIM))[tid];
  float dot = a.x * b.x + a.y * b.y + a.z * b.z + a.w * b.w;
  float na = a.x * a.x + a.y * a.y + a.z * a.z + a.w * a.w;
  float nb = b.x * b.x + b.y * b.y + b.z * b.z + b.w * b.w;
  int lane = tid & 63, wv = tid >> 6;
#pragma unroll
  for (int off = 32; off; off >>= 1) {
    dot += __shfl_xor(dot, off); na += __shfl_xor(na, off); nb += __shfl_xor(nb, off);
  }
  __shared__ float red[12];
  if (lane == 0) { red[wv] = dot; red[4 + wv] = na; red[8 + wv] = nb; }
  __syncthreads();
  if (tid == 0) {
    float d = red[0] + red[1] + red[2] + red[3];
    float x = red[4] + red[5] + red[6] + red[7];
    float y = red[8] + red[9] + red[10] + red[11];
    float den = fmaxf(sqrtf(x), 1e-8f) * fmaxf(sqrtf(y), 1e-8f);
    cosv[m] = d / den;
  }
}

__global__ __launch_bounds__(256)
void final_reduce(const float* __restrict__ cosv, float* __restrict__ out)
{
  int tid = threadIdx.x;
  float s = 0.f;
  for (int i = tid; i < M_TOK; i += 256) s += cosv[i];
  int lane = tid & 63, wv = tid >> 6;
#pragma unroll
  for (int off = 32; off; off >>= 1) s += __shfl_xor(s, off);
  __shared__ float red[4];
  if (lane == 0) red[wv] = s;
  __syncthreads();
  if (tid == 0) out[0] = 1.f - (red[0] + red[1] + red[2] + red[3]) * (1.f / M_TOK);
}

extern "C" void kernel_launch(void* const* d_in, const int* in_sizes, int n_in,
                              void* d_out, int out_size, void* d_ws, size_t ws_size,
                              hipStream_t stream)
{
  (void)in_sizes; (void)n_in; (void)out_size;
  const float* all_features = (const float*)d_in[0];
  const float* teacher = (const float*)d_in[1];
  const float* ln_gamma = (const float*)d_in[2];
  const float* ln_beta = (const float*)d_in[3];
  const float* norm_w = (const float*)d_in[4];
  const float* input_w = (const float*)d_in[5];
  const float* input_b = (const float*)d_in[6];
  const float* output_w = (const float*)d_in[7];
  const float* output_b = (const float*)d_in[8];
  float* out = (float*)d_out;
  char* ws = (char*)d_ws;

  const size_t M = M_TOK, D = DDIM, C = CDIM;
  const size_t xnB = 8 * M * D * 2;      // 134 MB
  const size_t wbB = 8 * C * D * 2;      // 67 MB
  const size_t owbB = C * C * 2;         // 2 MB
  const size_t voB = 8 * M * C * 2;      // 33.5 MB (bf16; slab7 = vin)
  const size_t fuseB = M * C * 2;
  const size_t vfB = M * C * 4;
  const size_t cosB = M * 4;
  const size_t fastTotal = xnB + wbB + owbB + voB + fuseB + vfB + cosB;

  if (ws_size >= fastTotal) {
    bf16_t* xn = (bf16_t*)ws;
    bf16_t* wb = (bf16_t*)(ws + xnB);
    bf16_t* owb = (bf16_t*)(ws + xnB + wbB);
    bf16_t* vo = (bf16_t*)(ws + xnB + wbB + owbB);
    bf16_t* fuse = (bf16_t*)(ws + xnB + wbB + owbB + voB);
    float* vf = (float*)(ws + xnB + wbB + owbB + voB + fuseB);
    float* cosv = (float*)(ws + xnB + wbB + owbB + voB + fuseB + vfB);

    cvt_bf16<<<4096, 256, 0, stream>>>(norm_w, wb, (long)7 * C * D);
    cvt_bf16<<<2048, 256, 0, stream>>>(input_w, wb + (size_t)7 * C * D, (long)(C * D));
    cvt_bf16<<<512, 256, 0, stream>>>(output_w, owb, (long)(C * C));
    dim3 g1((unsigned)M, 7);
    ln_convert<<<g1, 256, 0, stream>>>(all_features, ln_gamma, ln_beta, xn, 0, 1);
    gemm256<<<256, 512, 0, stream>>>(xn, wb, vo, input_b,
                                     (int)M, (int)C, (int)D, 0, 32, 4);
    attn_fuse<<<(unsigned)M, 512, 0, stream>>>(vo, fuse);
    gemm_bt_epi<<<128, 256, 0, stream>>>(fuse, owb, vf, output_b, vo + (size_t)7 * M * C,
                                         (int)M, (int)C, (int)C, 8);
    cos_row<<<(unsigned)M, 256, 0, stream>>>(vf, teacher, cosv);
    final_reduce<<<1, 256, 0, stream>>>(cosv, out);
  } else {
    // SMALL-ws fallback: loop j, reuse one xn/wb slab.
    const size_t xn1B = M * D * 2;
    const size_t wb1B = C * D * 2;
    bf16_t* xn1 = (bf16_t*)ws;
    bf16_t* wb1 = (bf16_t*)(ws + xn1B);
    bf16_t* owb = (bf16_t*)(ws + xn1B + wb1B);
    bf16_t* vo = (bf16_t*)(ws + xn1B + wb1B + owbB);
    bf16_t* fuse = (bf16_t*)(ws + xn1B + wb1B + owbB + voB);
    float* vf = (float*)(ws + xn1B + wb1B + owbB + voB + fuseB);
    float* cosv = (float*)(ws + xn1B + wb1B + owbB + voB + fuseB + vfB);

    cvt_bf16<<<512, 256, 0, stream>>>(output_w, owb, (long)(C * C));
    for (int j = 0; j < 8; ++j) {
      const float* wsrc = (j < 7) ? (norm_w + (size_t)j * C * D) : input_w;
      cvt_bf16<<<2048, 256, 0, stream>>>(wsrc, wb1, (long)(C * D));
      dim3 g1((unsigned)M, 1);
      ln_convert<<<g1, 256, 0, stream>>>(all_features, ln_gamma, ln_beta, xn1, j, 0);
      gemm256<<<32, 512, 0, stream>>>(xn1, wb1, vo, input_b,
                                      (int)M, (int)C, (int)D, j, 32, 4);
    }
    attn_fuse<<<(unsigned)M, 512, 0, stream>>>(vo, fuse);
    gemm_bt_epi<<<128, 256, 0, stream>>>(fuse, owb, vf, output_b, vo + (size_t)7 * M * C,
                                         (int)M, (int)C, (int)C, 8);
    cos_row<<<(unsigned)M, 256, 0, stream>>>(vf, teacher, cosv);
    final_reduce<<<1, 256, 0, stream>>>(cosv, out);
  }
}

// Round 9
// 266.655 us; speedup vs baseline: 1.0964x; 1.0927x over previous
//
#include <hip/hip_runtime.h>
#include <cstdint>
#include <cstring>

#define M_TOK 2048   // BT*S
#define DDIM 4096
#define CDIM 1024
#define LTOT 25

typedef __bf16 bf16_t;
typedef __attribute__((ext_vector_type(8))) __bf16 bf16x8;
typedef __attribute__((ext_vector_type(4))) float f32x4;

__device__ __forceinline__ void gload16(const void* g, void* l) {
  __builtin_amdgcn_global_load_lds(
      (const __attribute__((address_space(1))) unsigned int*)g,
      (__attribute__((address_space(3))) unsigned int*)l, 16, 0, 0);
}

// ---------------- fp32 -> bf16 convert (small-ws path only) ----------------
__global__ void cvt_bf16(const float* __restrict__ src, bf16_t* __restrict__ dst, long n) {
  long stride = (long)gridDim.x * blockDim.x;
  for (long i = (long)blockIdx.x * blockDim.x + threadIdx.x; i * 8 < n; i += stride) {
    const float4* s4 = (const float4*)(src + i * 8);
    float4 a = s4[0], b = s4[1];
    bf16_t o[8] = {(bf16_t)a.x, (bf16_t)a.y, (bf16_t)a.z, (bf16_t)a.w,
                   (bf16_t)b.x, (bf16_t)b.y, (bf16_t)b.z, (bf16_t)b.w};
    uint4 pk;
    __builtin_memcpy(&pk, o, 16);
    *(uint4*)(dst + i * 8) = pk;
  }
}

// ---------------- LayerNorm + gather + bf16 convert (small-ws path) ----------------
__global__ __launch_bounds__(256)
void ln_convert(const float* __restrict__ af, const float* __restrict__ gamma,
                const float* __restrict__ beta, bf16_t* __restrict__ xn,
                int jBase, int fuse7)
{
  int m = blockIdx.x;
  int jl = blockIdx.y;
  int j = jBase + jl;
  int layer = (j < 7) ? (24 - 4 * j) : 24;
  const float4* row4 = (const float4*)(af + ((size_t)m * LTOT + layer) * DDIM);
  int tid = threadIdx.x;
  float4 v[4];
  float s = 0.f, ss = 0.f;
#pragma unroll
  for (int i = 0; i < 4; ++i) {
    v[i] = row4[i * 256 + tid];
    s += v[i].x + v[i].y + v[i].z + v[i].w;
    ss += v[i].x * v[i].x + v[i].y * v[i].y + v[i].z * v[i].z + v[i].w * v[i].w;
  }
  int lane = tid & 63, wv = tid >> 6;
#pragma unroll
  for (int off = 32; off; off >>= 1) { s += __shfl_xor(s, off); ss += __shfl_xor(ss, off); }
  __shared__ float red[8];
  if (lane == 0) { red[wv] = s; red[4 + wv] = ss; }
  __syncthreads();
  s = red[0] + red[1] + red[2] + red[3];
  ss = red[4] + red[5] + red[6] + red[7];
  float mu = 0.f, rs = 1.f;
  if (j < 7) {
    mu = s * (1.f / DDIM);
    float var = ss * (1.f / DDIM) - mu * mu;
    rs = rsqrtf(var + 1e-5f);
  }
  if (fuse7 && jl == 0) {
    bf16_t* o7 = xn + ((size_t)7 * M_TOK + m) * DDIM;
#pragma unroll
    for (int i = 0; i < 4; ++i) {
      bf16_t o[4] = {(bf16_t)v[i].x, (bf16_t)v[i].y, (bf16_t)v[i].z, (bf16_t)v[i].w};
      uint2 pk;
      __builtin_memcpy(&pk, o, 8);
      ((uint2*)o7)[i * 256 + tid] = pk;
    }
  }
  bf16_t* orow = xn + ((size_t)jl * M_TOK + m) * DDIM;
  int jw = (j < 7) ? j : 0;
  const float4* g4 = (const float4*)(gamma + (size_t)jw * DDIM);
  const float4* b4 = (const float4*)(beta + (size_t)jw * DDIM);
#pragma unroll
  for (int i = 0; i < 4; ++i) {
    float4 x = v[i];
    float4 ov;
    if (j < 7) {
      float4 g = g4[i * 256 + tid], bb = b4[i * 256 + tid];
      ov.x = (x.x - mu) * rs * g.x + bb.x;
      ov.y = (x.y - mu) * rs * g.y + bb.y;
      ov.z = (x.z - mu) * rs * g.z + bb.z;
      ov.w = (x.w - mu) * rs * g.w + bb.w;
    } else ov = x;
    bf16_t o[4] = {(bf16_t)ov.x, (bf16_t)ov.y, (bf16_t)ov.z, (bf16_t)ov.w};
    uint2 pk;
    __builtin_memcpy(&pk, o, 8);
    ((uint2*)orow)[i * 256 + tid] = pk;
  }
}

// ---------------- fused prep: LN slabs (y<7, slab7 fused into y==0) + weight cvt (y==7) --
// wdst covers wb (8*C*D bf16: norm_w[0..6] + input_w) then owb (C*C) contiguously.
__global__ __launch_bounds__(256)
void prep(const float* __restrict__ af, const float* __restrict__ gamma,
          const float* __restrict__ beta, bf16_t* __restrict__ xn,
          const float* __restrict__ norm_w, const float* __restrict__ input_w,
          const float* __restrict__ output_w, bf16_t* __restrict__ wdst)
{
  int tid = threadIdx.x;
  if (blockIdx.y == 7) {
    // weight conversion: 8*C*D + C*C elems, grid-stride over 2048 blocks
    const long NW = (long)7 * CDIM * DDIM;
    const long NWI = (long)8 * CDIM * DDIM;
    const long total = NWI + (long)CDIM * CDIM;
    long stride = (long)gridDim.x * blockDim.x;
    for (long i = (long)blockIdx.x * blockDim.x + tid; i * 8 < total; i += stride) {
      long e = i * 8;
      const float* s;
      if (e < NW)       s = norm_w + e;
      else if (e < NWI) s = input_w + (e - NW);
      else              s = output_w + (e - NWI);
      const float4* s4 = (const float4*)s;
      float4 a = s4[0], b = s4[1];
      bf16_t o[8] = {(bf16_t)a.x, (bf16_t)a.y, (bf16_t)a.z, (bf16_t)a.w,
                     (bf16_t)b.x, (bf16_t)b.y, (bf16_t)b.z, (bf16_t)b.w};
      uint4 pk;
      __builtin_memcpy(&pk, o, 16);
      *(uint4*)(wdst + e) = pk;
    }
    return;
  }
  int m = blockIdx.x;
  int jl = blockIdx.y;
  int layer = 24 - 4 * jl;
  const float4* row4 = (const float4*)(af + ((size_t)m * LTOT + layer) * DDIM);
  float4 v[4];
  float s = 0.f, ss = 0.f;
#pragma unroll
  for (int i = 0; i < 4; ++i) {
    v[i] = row4[i * 256 + tid];
    s += v[i].x + v[i].y + v[i].z + v[i].w;
    ss += v[i].x * v[i].x + v[i].y * v[i].y + v[i].z * v[i].z + v[i].w * v[i].w;
  }
  int lane = tid & 63, wv = tid >> 6;
#pragma unroll
  for (int off = 32; off; off >>= 1) { s += __shfl_xor(s, off); ss += __shfl_xor(ss, off); }
  __shared__ float red[8];
  if (lane == 0) { red[wv] = s; red[4 + wv] = ss; }
  __syncthreads();
  s = red[0] + red[1] + red[2] + red[3];
  ss = red[4] + red[5] + red[6] + red[7];
  float mu = s * (1.f / DDIM);
  float var = ss * (1.f / DDIM) - mu * mu;
  float rs = rsqrtf(var + 1e-5f);
  // raw copy into slab 7 (layer 24 read by jl==0)
  if (jl == 0) {
    bf16_t* o7 = xn + ((size_t)7 * M_TOK + m) * DDIM;
#pragma unroll
    for (int i = 0; i < 4; ++i) {
      bf16_t o[4] = {(bf16_t)v[i].x, (bf16_t)v[i].y, (bf16_t)v[i].z, (bf16_t)v[i].w};
      uint2 pk;
      __builtin_memcpy(&pk, o, 8);
      ((uint2*)o7)[i * 256 + tid] = pk;
    }
  }
  bf16_t* orow = xn + ((size_t)jl * M_TOK + m) * DDIM;
  const float4* g4 = (const float4*)(gamma + (size_t)jl * DDIM);
  const float4* b4 = (const float4*)(beta + (size_t)jl * DDIM);
#pragma unroll
  for (int i = 0; i < 4; ++i) {
    float4 x = v[i];
    float4 g = g4[i * 256 + tid], bb = b4[i * 256 + tid];
    float4 ov;
    ov.x = (x.x - mu) * rs * g.x + bb.x;
    ov.y = (x.y - mu) * rs * g.y + bb.y;
    ov.z = (x.z - mu) * rs * g.z + bb.z;
    ov.w = (x.w - mu) * rs * g.w + bb.w;
    bf16_t o[4] = {(bf16_t)ov.x, (bf16_t)ov.y, (bf16_t)ov.z, (bf16_t)ov.w};
    uint2 pk;
    __builtin_memcpy(&pk, o, 8);
    ((uint2*)orow)[i * 256 + tid] = pk;
  }
}

// ---------------- 256x256-tile 8-phase batched B^T GEMM, deep-slack ladder -------
// (round-6 structure; trailing barriers of ph0/ph2 removed — audited safe:
//  next STAGE targets buffers whose last readers drained before an earlier barrier)
__global__ __launch_bounds__(512, 2)
void gemm256(const bf16_t* __restrict__ A, const bf16_t* __restrict__ B,
             bf16_t* __restrict__ Cout, const float* __restrict__ bias,
             int Mm, int Nn, int Kk, int jBase, int tilesPerJ, int tilesN)
{
  __shared__ __align__(16) char smem[131072];  // [0,64K) A bufs, [64K,128K) B bufs
  int nb = gridDim.x;
  int bid = blockIdx.x;
  if ((nb & 7) == 0) { int cpx = nb >> 3; bid = (bid & 7) * cpx + (bid >> 3); }  // XCD swizzle
  int jl = bid / tilesPerJ;
  int t0 = bid % tilesPerJ;
  int bm = t0 / tilesN, bn = t0 % tilesN;
  int jg = jBase + jl;

  const bf16_t* Aj = A + (size_t)jl * Mm * Kk + (size_t)bm * 256 * Kk;
  const bf16_t* Bj = B + (size_t)jl * Nn * Kk + (size_t)bn * 256 * Kk;

  int tid = threadIdx.x;
  int lane = tid & 63, wid = tid >> 6;
  int wm = wid >> 2, wn = wid & 3;
  int wm2 = wm * 2;

  const bf16_t* Ast = Aj + (size_t)(wid * 8 + (lane >> 3)) * Kk + ((lane & 7) ^ ((lane >> 3) & 7)) * 8;
  const bf16_t* Bst = Bj + (size_t)(wid * 8 + (lane >> 3)) * Kk + ((lane & 7) ^ ((lane >> 3) & 7)) * 8;

  int rb = lane & 15;
  int s0 = (((lane >> 4)) ^ (lane & 7)) * 16;      // k-slice 0 byte offset in 128B row
  int s1 = ((4 | (lane >> 4)) ^ (lane & 7)) * 16;  // k-slice 1

  int NT = Kk >> 6;
  f32x4 acc[8][4] = {};
  bf16x8 Af[4][2], Bf[4][2];

#define STAGEA(c_, tt_)                                                          \
  gload16(Ast + (size_t)(c_) * 64 * Kk + (size_t)(tt_) * 64,                     \
          &smem[(((tt_) & 1) * 32768) + (c_) * 8192 + wid * 1024])
#define STAGEB(c_, tt_)                                                          \
  gload16(Bst + (size_t)(c_) * 64 * Kk + (size_t)(tt_) * 64,                     \
          &smem[65536 + (((tt_) & 1) * 32768) + (c_) * 8192 + wid * 1024])

#define LOADA(buf_, ih_)                                                         \
  { const char* Ac_ = &smem[(buf_) * 32768 + (wm2 + (ih_)) * 8192];              \
    _Pragma("unroll")                                                            \
    for (int ip_ = 0; ip_ < 4; ++ip_) {                                          \
      Af[ip_][0] = *(const bf16x8*)(Ac_ + (ip_ * 16 + rb) * 128 + s0);           \
      Af[ip_][1] = *(const bf16x8*)(Ac_ + (ip_ * 16 + rb) * 128 + s1);           \
    } }

#define LOADB(buf_, jh_)                                                         \
  { const char* Bc_ = &smem[65536 + (buf_) * 32768 + wn * 8192];                 \
    _Pragma("unroll")                                                            \
    for (int jp_ = 0; jp_ < 2; ++jp_) {                                          \
      Bf[(jh_) * 2 + jp_][0] = *(const bf16x8*)(Bc_ + (((jh_) * 2 + jp_) * 16 + rb) * 128 + s0); \
      Bf[(jh_) * 2 + jp_][1] = *(const bf16x8*)(Bc_ + (((jh_) * 2 + jp_) * 16 + rb) * 128 + s1); \
    } }

#define MFMAQ(ih_, jh_)                                                          \
  { __builtin_amdgcn_s_setprio(1);                                               \
    _Pragma("unroll")                                                            \
    for (int ip_ = 0; ip_ < 4; ++ip_)                                            \
      _Pragma("unroll")                                                          \
      for (int jp_ = 0; jp_ < 2; ++jp_)                                          \
        _Pragma("unroll")                                                        \
        for (int k_ = 0; k_ < 2; ++k_)                                           \
          acc[(ih_) * 4 + ip_][(jh_) * 2 + jp_] =                                \
              __builtin_amdgcn_mfma_f32_16x16x32_bf16(                           \
                  Af[ip_][k_], Bf[(jh_) * 2 + jp_][k_],                          \
                  acc[(ih_) * 4 + ip_][(jh_) * 2 + jp_], 0, 0, 0);               \
    __builtin_amdgcn_s_setprio(0); }

#define BAR() asm volatile("s_barrier" ::: "memory")
#define LGKM0() asm volatile("s_waitcnt lgkmcnt(0)" ::: "memory")

  // prologue: tile 0 (8 loads) + A0,A2 of tile 1 = 10 in flight
  STAGEB(0, 0); STAGEB(1, 0); STAGEB(2, 0); STAGEB(3, 0);
  STAGEA(0, 0); STAGEA(2, 0); STAGEA(1, 0); STAGEA(3, 0);
  if (NT > 1) { STAGEA(0, 1); STAGEA(2, 1); }
  asm volatile("s_waitcnt vmcnt(4)" ::: "memory");  // tile-0 B*,A0,A2 landed
  BAR();

#pragma unroll 1
  for (int t = 0; t < NT; ++t) {
    int buf = t & 1;
    // ---- phase 0: quadrant (0,0); stage B0,B1(t+1) ----
    LOADA(buf, 0);
    LOADB(buf, 0);
    if (t + 1 < NT) { STAGEB(0, t + 1); STAGEB(1, t + 1); }
    BAR(); LGKM0();
    MFMAQ(0, 0);
    // (trailing barrier removed — audited safe)
    // ---- phase 1: quadrant (0,1); stage B2,B3(t+1); wait A1,A3(t) drained ----
    LOADB(buf, 1);
    if (t + 1 < NT) { STAGEB(2, t + 1); STAGEB(3, t + 1); }
    BAR(); LGKM0();
    MFMAQ(0, 1);
    if (t + 1 < NT) asm volatile("s_waitcnt vmcnt(6)" ::: "memory");
    else            asm volatile("s_waitcnt vmcnt(0)" ::: "memory");
    BAR();
    // ---- phase 2: quadrant (1,0); stage A1,A3(t+1) ----
    LOADA(buf, 1);
    if (t + 1 < NT) { STAGEA(1, t + 1); STAGEA(3, t + 1); }
    BAR(); LGKM0();
    MFMAQ(1, 0);
    // (trailing barrier removed — audited safe)
    // ---- phase 3: quadrant (1,1); stage A0,A2(t+2); wait t+1 B*,A0,A2 ----
    if (t + 2 < NT) { STAGEA(0, t + 2); STAGEA(2, t + 2); }
    BAR(); LGKM0();
    MFMAQ(1, 1);
    if (t + 2 < NT)      asm volatile("s_waitcnt vmcnt(4)" ::: "memory");
    else if (t + 1 < NT) asm volatile("s_waitcnt vmcnt(2)" ::: "memory");
    BAR();
  }
#undef STAGEA
#undef STAGEB
#undef LOADA
#undef LOADB
#undef MFMAQ
#undef BAR
#undef LGKM0

  int rowBase = bm * 256 + wm * 128 + (lane >> 4) * 4;
  int colBase = bn * 256 + wn * 64 + (lane & 15);
  bf16_t* Cj = Cout + (size_t)jg * Mm * Nn;
#pragma unroll
  for (int i = 0; i < 8; ++i) {
#pragma unroll
    for (int j = 0; j < 4; ++j) {
      int gn = colBase + j * 16;
      float bv = (jg == 7) ? bias[gn] : 0.f;
#pragma unroll
      for (int r = 0; r < 4; ++r) {
        int gm = rowBase + i * 16 + r;
        Cj[(size_t)gm * Nn + gn] = (bf16_t)(acc[i][j][r] + bv);
      }
    }
  }
}

// ---------------- 128x128-tile GEMM for the output projection ----------------
__global__ __launch_bounds__(256)
void gemm_bt_epi(const bf16_t* __restrict__ A, const bf16_t* __restrict__ B,
                 float* __restrict__ Cout, const float* __restrict__ bias,
                 const bf16_t* __restrict__ vin, int Mm, int Nn, int Kk, int tilesN)
{
  __shared__ bf16_t As[128 * 64];
  __shared__ bf16_t Bs[128 * 64];
  int bid = blockIdx.x;
  int bm = bid / tilesN, bn = bid % tilesN;
  const bf16_t* Aj = A + (size_t)bm * 128 * Kk;
  const bf16_t* Bj = B + (size_t)bn * 128 * Kk;

  int tid = threadIdx.x;
  int lane = tid & 63, wv = tid >> 6;
  int wm = wv >> 1, wn = wv & 1;

  f32x4 acc[4][4] = {};

  int srow = wv * 32 + (lane >> 3);
  int scol = (lane & 7) * 8;
  const bf16_t* Ag = Aj + (size_t)srow * Kk + scol;
  const bf16_t* Bg = Bj + (size_t)srow * Kk + scol;

  for (int kt = 0; kt < Kk; kt += 64) {
#pragma unroll
    for (int c = 0; c < 4; ++c) {
      gload16(Ag + kt + (size_t)(c * 8) * Kk, &As[(wv * 32 + c * 8) * 64]);
      gload16(Bg + kt + (size_t)(c * 8) * Kk, &Bs[(wv * 32 + c * 8) * 64]);
    }
    __syncthreads();
#pragma unroll
    for (int ks = 0; ks < 2; ++ks) {
      int ko = ks * 32 + (lane >> 4) * 8;
      bf16x8 af[4], bfr[4];
#pragma unroll
      for (int i = 0; i < 4; ++i) {
        af[i] = *(const bf16x8*)&As[(wm * 64 + i * 16 + (lane & 15)) * 64 + ko];
        bfr[i] = *(const bf16x8*)&Bs[(wn * 64 + i * 16 + (lane & 15)) * 64 + ko];
      }
#pragma unroll
      for (int i = 0; i < 4; ++i)
#pragma unroll
        for (int j2 = 0; j2 < 4; ++j2)
          acc[i][j2] = __builtin_amdgcn_mfma_f32_16x16x32_bf16(af[i], bfr[j2], acc[i][j2], 0, 0, 0);
    }
    __syncthreads();
  }

  int rowBase = bm * 128 + wm * 64 + (lane >> 4) * 4;
  int colBase = bn * 128 + wn * 64 + (lane & 15);
#pragma unroll
  for (int i = 0; i < 4; ++i) {
#pragma unroll
    for (int j2 = 0; j2 < 4; ++j2) {
      int gn = colBase + j2 * 16;
      float bv = bias[gn];
#pragma unroll
      for (int r = 0; r < 4; ++r) {
        int gm = rowBase + i * 16 + r;
        Cout[(size_t)gm * Nn + gn] = acc[i][j2][r] + bv + (float)vin[(size_t)gm * Nn + gn];
      }
    }
  }
}

// ---------------- attention over 6 kv slabs (vo bf16) ----------------
__global__ __launch_bounds__(512)
void attn_fuse(const bf16_t* __restrict__ vo, bf16_t* __restrict__ fuse)
{
  int m = blockIdx.x;
  int h = threadIdx.x >> 6;
  int lane = threadIdx.x & 63;
  const size_t slab = (size_t)M_TOK * CDIM;
  const bf16_t* base = vo + (size_t)m * CDIM + h * 128;
  float q0 = (float)base[lane], q1 = (float)base[lane + 64];
  float kv0[6], kv1[6], sc[6];
#pragma unroll
  for (int k = 0; k < 6; ++k) {
    const bf16_t* kb = base + (size_t)(k + 1) * slab;
    kv0[k] = (float)kb[lane]; kv1[k] = (float)kb[lane + 64];
    sc[k] = q0 * kv0[k] + q1 * kv1[k];
  }
#pragma unroll
  for (int k = 0; k < 6; ++k) {
#pragma unroll
    for (int off = 32; off; off >>= 1) sc[k] += __shfl_xor(sc[k], off);
    sc[k] *= 0.03125f;  // C^-0.5
  }
  float mx = sc[0];
#pragma unroll
  for (int k = 1; k < 6; ++k) mx = fmaxf(mx, sc[k]);
  float e[6], se = 0.f;
#pragma unroll
  for (int k = 0; k < 6; ++k) { e[k] = expf(sc[k] - mx); se += e[k]; }
  float inv = 1.f / se;
  float f0 = 0.f, f1 = 0.f;
#pragma unroll
  for (int k = 0; k < 6; ++k) { float w = e[k] * inv; f0 += w * kv0[k]; f1 += w * kv1[k]; }
  bf16_t* o = fuse + (size_t)m * CDIM + h * 128;
  o[lane] = (bf16_t)f0;
  o[lane + 64] = (bf16_t)f1;
}

// ---------------- cosine per row ----------------
__global__ __launch_bounds__(256)
void cos_row(const float* __restrict__ vf, const float* __restrict__ teacher, float* __restrict__ cosv)
{
  int m = blockIdx.x;
  int tid = threadIdx.x;
  float4 a = ((const float4*)(vf + (size_t)m * CDIM))[tid];
  float4 b = ((const float4*)(teacher + (size_t)m * CDIM))[tid];
  float dot = a.x * b.x + a.y * b.y + a.z * b.z + a.w * b.w;
  float na = a.x * a.x + a.y * a.y + a.z * a.z + a.w * a.w;
  float nb = b.x * b.x + b.y * b.y + b.z * b.z + b.w * b.w;
  int lane = tid & 63, wv = tid >> 6;
#pragma unroll
  for (int off = 32; off; off >>= 1) {
    dot += __shfl_xor(dot, off); na += __shfl_xor(na, off); nb += __shfl_xor(nb, off);
  }
  __shared__ float red[12];
  if (lane == 0) { red[wv] = dot; red[4 + wv] = na; red[8 + wv] = nb; }
  __syncthreads();
  if (tid == 0) {
    float d = red[0] + red[1] + red[2] + red[3];
    float x = red[4] + red[5] + red[6] + red[7];
    float y = red[8] + red[9] + red[10] + red[11];
    float den = fmaxf(sqrtf(x), 1e-8f) * fmaxf(sqrtf(y), 1e-8f);
    cosv[m] = d / den;
  }
}

__global__ __launch_bounds__(256)
void final_reduce(const float* __restrict__ cosv, float* __restrict__ out)
{
  int tid = threadIdx.x;
  float s = 0.f;
  for (int i = tid; i < M_TOK; i += 256) s += cosv[i];
  int lane = tid & 63, wv = tid >> 6;
#pragma unroll
  for (int off = 32; off; off >>= 1) s += __shfl_xor(s, off);
  __shared__ float red[4];
  if (lane == 0) red[wv] = s;
  __syncthreads();
  if (tid == 0) out[0] = 1.f - (red[0] + red[1] + red[2] + red[3]) * (1.f / M_TOK);
}

extern "C" void kernel_launch(void* const* d_in, const int* in_sizes, int n_in,
                              void* d_out, int out_size, void* d_ws, size_t ws_size,
                              hipStream_t stream)
{
  (void)in_sizes; (void)n_in; (void)out_size;
  const float* all_features = (const float*)d_in[0];
  const float* teacher = (const float*)d_in[1];
  const float* ln_gamma = (const float*)d_in[2];
  const float* ln_beta = (const float*)d_in[3];
  const float* norm_w = (const float*)d_in[4];
  const float* input_w = (const float*)d_in[5];
  const float* input_b = (const float*)d_in[6];
  const float* output_w = (const float*)d_in[7];
  const float* output_b = (const float*)d_in[8];
  float* out = (float*)d_out;
  char* ws = (char*)d_ws;

  const size_t M = M_TOK, D = DDIM, C = CDIM;
  const size_t xnB = 8 * M * D * 2;      // 134 MB
  const size_t wbB = 8 * C * D * 2;      // 67 MB
  const size_t owbB = C * C * 2;         // 2 MB
  const size_t voB = 8 * M * C * 2;      // 33.5 MB (bf16; slab7 = vin)
  const size_t fuseB = M * C * 2;
  const size_t vfB = M * C * 4;
  const size_t cosB = M * 4;
  const size_t fastTotal = xnB + wbB + owbB + voB + fuseB + vfB + cosB;

  if (ws_size >= fastTotal) {
    bf16_t* xn = (bf16_t*)ws;
    bf16_t* wb = (bf16_t*)(ws + xnB);           // wb (8*C*D) then owb (C*C) contiguous
    bf16_t* owb = (bf16_t*)(ws + xnB + wbB);
    bf16_t* vo = (bf16_t*)(ws + xnB + wbB + owbB);
    bf16_t* fuse = (bf16_t*)(ws + xnB + wbB + owbB + voB);
    float* vf = (float*)(ws + xnB + wbB + owbB + voB + fuseB);
    float* cosv = (float*)(ws + xnB + wbB + owbB + voB + fuseB + vfB);

    dim3 gp((unsigned)M, 8);
    prep<<<gp, 256, 0, stream>>>(all_features, ln_gamma, ln_beta, xn,
                                 norm_w, input_w, output_w, wb);
    gemm256<<<256, 512, 0, stream>>>(xn, wb, vo, input_b,
                                     (int)M, (int)C, (int)D, 0, 32, 4);
    attn_fuse<<<(unsigned)M, 512, 0, stream>>>(vo, fuse);
    gemm_bt_epi<<<128, 256, 0, stream>>>(fuse, owb, vf, output_b, vo + (size_t)7 * M * C,
                                         (int)M, (int)C, (int)C, 8);
    cos_row<<<(unsigned)M, 256, 0, stream>>>(vf, teacher, cosv);
    final_reduce<<<1, 256, 0, stream>>>(cosv, out);
  } else {
    // SMALL-ws fallback: loop j, reuse one xn/wb slab.
    const size_t xn1B = M * D * 2;
    const size_t wb1B = C * D * 2;
    bf16_t* xn1 = (bf16_t*)ws;
    bf16_t* wb1 = (bf16_t*)(ws + xn1B);
    bf16_t* owb = (bf16_t*)(ws + xn1B + wb1B);
    bf16_t* vo = (bf16_t*)(ws + xn1B + wb1B + owbB);
    bf16_t* fuse = (bf16_t*)(ws + xn1B + wb1B + owbB + voB);
    float* vf = (float*)(ws + xn1B + wb1B + owbB + voB + fuseB);
    float* cosv = (float*)(ws + xn1B + wb1B + owbB + voB + fuseB + vfB);

    cvt_bf16<<<512, 256, 0, stream>>>(output_w, owb, (long)(C * C));
    for (int j = 0; j < 8; ++j) {
      const float* wsrc = (j < 7) ? (norm_w + (size_t)j * C * D) : input_w;
      cvt_bf16<<<2048, 256, 0, stream>>>(wsrc, wb1, (long)(C * D));
      dim3 g1((unsigned)M, 1);
      ln_convert<<<g1, 256, 0, stream>>>(all_features, ln_gamma, ln_beta, xn1, j, 0);
      gemm256<<<32, 512, 0, stream>>>(xn1, wb1, vo, input_b,
                                      (int)M, (int)C, (int)D, j, 32, 4);
    }
    attn_fuse<<<(unsigned)M, 512, 0, stream>>>(vo, fuse);
    gemm_bt_epi<<<128, 256, 0, stream>>>(fuse, owb, vf, output_b, vo + (size_t)7 * M * C,
                                         (int)M, (int)C, (int)C, 8);
    cos_row<<<(unsigned)M, 256, 0, stream>>>(vf, teacher, cosv);
    final_reduce<<<1, 256, 0, stream>>>(cosv, out);
  }
}

// Round 10
// 236.001 us; speedup vs baseline: 1.2389x; 1.1299x over previous
//
#include <hip/hip_runtime.h>
#include <cstdint>
#include <cstring>

#define M_TOK 2048   // BT*S
#define DDIM 4096
#define CDIM 1024
#define LTOT 25

typedef __bf16 bf16_t;
typedef __attribute__((ext_vector_type(8))) __bf16 bf16x8;
typedef __attribute__((ext_vector_type(4))) float f32x4;
typedef unsigned char u8;

__device__ __forceinline__ void gload16(const void* g, void* l) {
  __builtin_amdgcn_global_load_lds(
      (const __attribute__((address_space(1))) unsigned int*)g,
      (__attribute__((address_space(3))) unsigned int*)l, 16, 0, 0);
}

__device__ __forceinline__ unsigned int pk4_fp8(float x, float y, float z, float w) {
  int r = __builtin_amdgcn_cvt_pk_fp8_f32(x, y, 0, false);   // bytes 0,1
  r = __builtin_amdgcn_cvt_pk_fp8_f32(z, w, r, true);        // bytes 2,3
  return (unsigned int)r;
}

// ---------------- fp32 -> fp8 convert (small-ws path) ----------------
__global__ void cvt_fp8(const float* __restrict__ src, u8* __restrict__ dst, long n) {
  long stride = (long)gridDim.x * blockDim.x;
  for (long i = (long)blockIdx.x * blockDim.x + threadIdx.x; i * 8 < n; i += stride) {
    const float4* s4 = (const float4*)(src + i * 8);
    float4 a = s4[0], b = s4[1];
    uint2 pk;
    pk.x = pk4_fp8(a.x, a.y, a.z, a.w);
    pk.y = pk4_fp8(b.x, b.y, b.z, b.w);
    *(uint2*)(dst + i * 8) = pk;
  }
}

// ---------------- fp32 -> bf16 convert (owb, small-ws path) ----------------
__global__ void cvt_bf16(const float* __restrict__ src, bf16_t* __restrict__ dst, long n) {
  long stride = (long)gridDim.x * blockDim.x;
  for (long i = (long)blockIdx.x * blockDim.x + threadIdx.x; i * 8 < n; i += stride) {
    const float4* s4 = (const float4*)(src + i * 8);
    float4 a = s4[0], b = s4[1];
    bf16_t o[8] = {(bf16_t)a.x, (bf16_t)a.y, (bf16_t)a.z, (bf16_t)a.w,
                   (bf16_t)b.x, (bf16_t)b.y, (bf16_t)b.z, (bf16_t)b.w};
    uint4 pk;
    __builtin_memcpy(&pk, o, 16);
    *(uint4*)(dst + i * 8) = pk;
  }
}

// ---------------- LayerNorm + gather + fp8 convert (small-ws path) ----------------
__global__ __launch_bounds__(256)
void ln_convert(const float* __restrict__ af, const float* __restrict__ gamma,
                const float* __restrict__ beta, u8* __restrict__ xn,
                int jBase, int fuse7)
{
  int m = blockIdx.x;
  int jl = blockIdx.y;
  int j = jBase + jl;
  int layer = (j < 7) ? (24 - 4 * j) : 24;
  const float4* row4 = (const float4*)(af + ((size_t)m * LTOT + layer) * DDIM);
  int tid = threadIdx.x;
  float4 v[4];
  float s = 0.f, ss = 0.f;
#pragma unroll
  for (int i = 0; i < 4; ++i) {
    v[i] = row4[i * 256 + tid];
    s += v[i].x + v[i].y + v[i].z + v[i].w;
    ss += v[i].x * v[i].x + v[i].y * v[i].y + v[i].z * v[i].z + v[i].w * v[i].w;
  }
  int lane = tid & 63, wv = tid >> 6;
#pragma unroll
  for (int off = 32; off; off >>= 1) { s += __shfl_xor(s, off); ss += __shfl_xor(ss, off); }
  __shared__ float red[8];
  if (lane == 0) { red[wv] = s; red[4 + wv] = ss; }
  __syncthreads();
  s = red[0] + red[1] + red[2] + red[3];
  ss = red[4] + red[5] + red[6] + red[7];
  float mu = 0.f, rs = 1.f;
  if (j < 7) {
    mu = s * (1.f / DDIM);
    float var = ss * (1.f / DDIM) - mu * mu;
    rs = rsqrtf(var + 1e-5f);
  }
  if (fuse7 && jl == 0) {
    u8* o7 = xn + ((size_t)7 * M_TOK + m) * DDIM;
#pragma unroll
    for (int i = 0; i < 4; ++i)
      ((unsigned int*)o7)[i * 256 + tid] = pk4_fp8(v[i].x, v[i].y, v[i].z, v[i].w);
  }
  u8* orow = xn + ((size_t)jl * M_TOK + m) * DDIM;
  int jw = (j < 7) ? j : 0;
  const float4* g4 = (const float4*)(gamma + (size_t)jw * DDIM);
  const float4* b4 = (const float4*)(beta + (size_t)jw * DDIM);
#pragma unroll
  for (int i = 0; i < 4; ++i) {
    float4 x = v[i];
    float4 ov;
    if (j < 7) {
      float4 g = g4[i * 256 + tid], bb = b4[i * 256 + tid];
      ov.x = (x.x - mu) * rs * g.x + bb.x;
      ov.y = (x.y - mu) * rs * g.y + bb.y;
      ov.z = (x.z - mu) * rs * g.z + bb.z;
      ov.w = (x.w - mu) * rs * g.w + bb.w;
    } else ov = x;
    ((unsigned int*)orow)[i * 256 + tid] = pk4_fp8(ov.x, ov.y, ov.z, ov.w);
  }
}

// ---------------- fused prep: LN->fp8 slabs (y<7, slab7 in y==0) + weight cvt (y==7) --
// wb8: 8*C*D fp8 (norm_w[0..6] + input_w); owb: C*C bf16 (separate ptr).
__global__ __launch_bounds__(256)
void prep(const float* __restrict__ af, const float* __restrict__ gamma,
          const float* __restrict__ beta, u8* __restrict__ xn,
          const float* __restrict__ norm_w, const float* __restrict__ input_w,
          const float* __restrict__ output_w, u8* __restrict__ wb8,
          bf16_t* __restrict__ owb)
{
  int tid = threadIdx.x;
  if (blockIdx.y == 7) {
    const long NW7 = (long)7 * CDIM * DDIM;
    const long NWI = (long)8 * CDIM * DDIM;
    const long TOT = NWI + (long)CDIM * CDIM;
    long stride = (long)gridDim.x * blockDim.x;
    for (long i = (long)blockIdx.x * blockDim.x + tid; i * 8 < TOT; i += stride) {
      long e = i * 8;
      const float* sp;
      if (e < NW7)      sp = norm_w + e;
      else if (e < NWI) sp = input_w + (e - NW7);
      else              sp = output_w + (e - NWI);
      const float4* s4 = (const float4*)sp;
      float4 a = s4[0], b = s4[1];
      if (e < NWI) {
        uint2 pk;
        pk.x = pk4_fp8(a.x, a.y, a.z, a.w);
        pk.y = pk4_fp8(b.x, b.y, b.z, b.w);
        *(uint2*)(wb8 + e) = pk;
      } else {
        bf16_t o[8] = {(bf16_t)a.x, (bf16_t)a.y, (bf16_t)a.z, (bf16_t)a.w,
                       (bf16_t)b.x, (bf16_t)b.y, (bf16_t)b.z, (bf16_t)b.w};
        uint4 pk;
        __builtin_memcpy(&pk, o, 16);
        *(uint4*)(owb + (e - NWI)) = pk;
      }
    }
    return;
  }
  int m = blockIdx.x;
  int jl = blockIdx.y;
  int layer = 24 - 4 * jl;
  const float4* row4 = (const float4*)(af + ((size_t)m * LTOT + layer) * DDIM);
  float4 v[4];
  float s = 0.f, ss = 0.f;
#pragma unroll
  for (int i = 0; i < 4; ++i) {
    v[i] = row4[i * 256 + tid];
    s += v[i].x + v[i].y + v[i].z + v[i].w;
    ss += v[i].x * v[i].x + v[i].y * v[i].y + v[i].z * v[i].z + v[i].w * v[i].w;
  }
  int lane = tid & 63, wv = tid >> 6;
#pragma unroll
  for (int off = 32; off; off >>= 1) { s += __shfl_xor(s, off); ss += __shfl_xor(ss, off); }
  __shared__ float red[8];
  if (lane == 0) { red[wv] = s; red[4 + wv] = ss; }
  __syncthreads();
  s = red[0] + red[1] + red[2] + red[3];
  ss = red[4] + red[5] + red[6] + red[7];
  float mu = s * (1.f / DDIM);
  float var = ss * (1.f / DDIM) - mu * mu;
  float rs = rsqrtf(var + 1e-5f);
  if (jl == 0) {
    u8* o7 = xn + ((size_t)7 * M_TOK + m) * DDIM;
#pragma unroll
    for (int i = 0; i < 4; ++i)
      ((unsigned int*)o7)[i * 256 + tid] = pk4_fp8(v[i].x, v[i].y, v[i].z, v[i].w);
  }
  u8* orow = xn + ((size_t)jl * M_TOK + m) * DDIM;
  const float4* g4 = (const float4*)(gamma + (size_t)jl * DDIM);
  const float4* b4 = (const float4*)(beta + (size_t)jl * DDIM);
#pragma unroll
  for (int i = 0; i < 4; ++i) {
    float4 x = v[i];
    float4 g = g4[i * 256 + tid], bb = b4[i * 256 + tid];
    float4 ov;
    ov.x = (x.x - mu) * rs * g.x + bb.x;
    ov.y = (x.y - mu) * rs * g.y + bb.y;
    ov.z = (x.z - mu) * rs * g.z + bb.z;
    ov.w = (x.w - mu) * rs * g.w + bb.w;
    ((unsigned int*)orow)[i * 256 + tid] = pk4_fp8(ov.x, ov.y, ov.z, ov.w);
  }
}

// ------ 256x256-tile fp8 batched B^T GEMM: ring-4 LDS, 3-tiles-ahead staging ------
// C[jg][m][n] = bf16( sum_k A[jl][m][k]*B[jl][n][k] (+bias) ), A,B fp8 e4m3.
// 512 threads = 8 waves (2 wm x 4 wn); per-wave output 128x64. BK=64.
// mfma_f32_16x16x32_fp8_fp8 (A/B = 8 fp8 = 1 x b64). 64 MFMA/wave/tile.
// LDS: ring-4 x (A 16 KB + B 16 KB) = 128 KB. Tile t staged during tile t-3.
// ONE vmcnt + ONE barrier per K-tile (no intra-tile waits; slack = 3 tiles).
// Swizzle: row r stores global 8B-slot s at s^(((r>>1)&3)<<1); linear gload dest,
// source 16B-pair pre-swizzle (lane&3)^((lane>>3)&3); reads uniform 4 lanes/bank.
__global__ __launch_bounds__(512, 2)
void gemm256f8(const u8* __restrict__ A, const u8* __restrict__ B,
               bf16_t* __restrict__ Cout, const float* __restrict__ bias,
               int Mm, int Nn, int Kk, int jBase, int tilesPerJ, int tilesN)
{
  __shared__ __align__(16) u8 smem[131072];   // [0,64K) A ring, [64K,128K) B ring
  int nb = gridDim.x;
  int bid = blockIdx.x;
  if ((nb & 7) == 0) { int cpx = nb >> 3; bid = (bid & 7) * cpx + (bid >> 3); }  // XCD swizzle
  int jl = bid / tilesPerJ;
  int t0 = bid % tilesPerJ;
  int bm = t0 / tilesN, bn = t0 % tilesN;
  int jg = jBase + jl;

  const u8* Aj = A + (size_t)jl * Mm * Kk + (size_t)bm * 256 * Kk;
  const u8* Bj = B + (size_t)jl * Nn * Kk + (size_t)bn * 256 * Kk;

  int tid = threadIdx.x;
  int lane = tid & 63, wid = tid >> 6;
  int wm = wid >> 2, wn = wid & 3;

  // staging: issue h covers rows 128h + wid*16 + (lane>>2); 16B pair = lane&3
  // source pre-swizzle: pair p of row r holds global pair p ^ ((r>>1)&3)
  int srow = wid * 16 + (lane >> 2);
  int spre = ((lane & 3) ^ ((lane >> 3) & 3)) * 16;
  const u8* Ast = Aj + (size_t)srow * Kk + spre;
  const u8* Bst = Bj + (size_t)srow * Kk + spre;

  // read addressing: frag row rb=lane&15; global slot s = ks*4+(lane>>4);
  // stored slot = s ^ (((lane>>1)&3)<<1); byte = slot*8
  int rb64 = (lane & 15) * 64;
  int swz = ((lane >> 1) & 3) << 1;
  int so0 = (((lane >> 4)) ^ swz) * 8;
  int so1 = (((lane >> 4) | 4) ^ swz) * 8;

  int NT = Kk >> 6;
  f32x4 acc[8][4] = {};
  long long Af[8][2], Bf[4][2];

#define STAGE4(tt_)                                                              \
  { gload16(Ast + (size_t)(tt_) * 64,                 &smem[((tt_) & 3) * 16384 + wid * 1024]); \
    gload16(Ast + (size_t)128 * Kk + (size_t)(tt_) * 64, &smem[((tt_) & 3) * 16384 + 8192 + wid * 1024]); \
    gload16(Bst + (size_t)(tt_) * 64,                 &smem[65536 + ((tt_) & 3) * 16384 + wid * 1024]); \
    gload16(Bst + (size_t)128 * Kk + (size_t)(tt_) * 64, &smem[65536 + ((tt_) & 3) * 16384 + 8192 + wid * 1024]); }

#define BAR() asm volatile("s_barrier" ::: "memory")

  // prologue: stage tiles 0,1,2
  STAGE4(0);
  if (NT > 1) STAGE4(1);
  if (NT > 2) STAGE4(2);
  if (NT > 2)      asm volatile("s_waitcnt vmcnt(8)" ::: "memory");
  else if (NT > 1) asm volatile("s_waitcnt vmcnt(4)" ::: "memory");
  else             asm volatile("s_waitcnt vmcnt(0)" ::: "memory");
  BAR();

#pragma unroll 1
  for (int t = 0; t < NT; ++t) {
    const u8* Ab = &smem[(t & 3) * 16384 + wm * 8192];
    const u8* Bb = &smem[65536 + (t & 3) * 16384 + wn * 4096];
#pragma unroll
    for (int ip = 0; ip < 8; ++ip) {
      Af[ip][0] = *(const long long*)(Ab + ip * 1024 + rb64 + so0);
      Af[ip][1] = *(const long long*)(Ab + ip * 1024 + rb64 + so1);
    }
#pragma unroll
    for (int jp = 0; jp < 4; ++jp) {
      Bf[jp][0] = *(const long long*)(Bb + jp * 1024 + rb64 + so0);
      Bf[jp][1] = *(const long long*)(Bb + jp * 1024 + rb64 + so1);
    }
    if (t + 3 < NT) STAGE4(t + 3);
    __builtin_amdgcn_s_setprio(1);
#pragma unroll
    for (int ip = 0; ip < 8; ++ip)
#pragma unroll
      for (int jp = 0; jp < 4; ++jp)
#pragma unroll
        for (int ks = 0; ks < 2; ++ks)
          acc[ip][jp] = __builtin_amdgcn_mfma_f32_16x16x32_fp8_fp8(
              Af[ip][ks], Bf[jp][ks], acc[ip][jp], 0, 0, 0);
    __builtin_amdgcn_s_setprio(0);
    if (t + 1 < NT) {
      asm volatile("s_waitcnt lgkmcnt(0)" ::: "memory");   // reads of buf t drained
      if (t + 3 < NT)      asm volatile("s_waitcnt vmcnt(8)" ::: "memory");
      else if (t + 2 < NT) asm volatile("s_waitcnt vmcnt(4)" ::: "memory");
      else                 asm volatile("s_waitcnt vmcnt(0)" ::: "memory");
      BAR();
    }
  }
#undef STAGE4
#undef BAR

  int rowBase = bm * 256 + wm * 128 + (lane >> 4) * 4;
  int colBase = bn * 256 + wn * 64 + (lane & 15);
  bf16_t* Cj = Cout + (size_t)jg * Mm * Nn;
#pragma unroll
  for (int i = 0; i < 8; ++i) {
#pragma unroll
    for (int j = 0; j < 4; ++j) {
      int gn = colBase + j * 16;
      float bv = (jg == 7) ? bias[gn] : 0.f;
#pragma unroll
      for (int r = 0; r < 4; ++r) {
        int gm = rowBase + i * 16 + r;
        Cj[(size_t)gm * Nn + gn] = (bf16_t)(acc[i][j][r] + bv);
      }
    }
  }
}

// ---------------- 128x128-tile bf16 GEMM for the output projection ----------------
__global__ __launch_bounds__(256)
void gemm_bt_epi(const bf16_t* __restrict__ A, const bf16_t* __restrict__ B,
                 float* __restrict__ Cout, const float* __restrict__ bias,
                 const bf16_t* __restrict__ vin, int Mm, int Nn, int Kk, int tilesN)
{
  __shared__ bf16_t As[128 * 64];
  __shared__ bf16_t Bs[128 * 64];
  int bid = blockIdx.x;
  int bm = bid / tilesN, bn = bid % tilesN;
  const bf16_t* Aj = A + (size_t)bm * 128 * Kk;
  const bf16_t* Bj = B + (size_t)bn * 128 * Kk;

  int tid = threadIdx.x;
  int lane = tid & 63, wv = tid >> 6;
  int wm = wv >> 1, wn = wv & 1;

  f32x4 acc[4][4] = {};

  int srow = wv * 32 + (lane >> 3);
  int scol = (lane & 7) * 8;
  const bf16_t* Ag = Aj + (size_t)srow * Kk + scol;
  const bf16_t* Bg = Bj + (size_t)srow * Kk + scol;

  for (int kt = 0; kt < Kk; kt += 64) {
#pragma unroll
    for (int c = 0; c < 4; ++c) {
      gload16(Ag + kt + (size_t)(c * 8) * Kk, &As[(wv * 32 + c * 8) * 64]);
      gload16(Bg + kt + (size_t)(c * 8) * Kk, &Bs[(wv * 32 + c * 8) * 64]);
    }
    __syncthreads();
#pragma unroll
    for (int ks = 0; ks < 2; ++ks) {
      int ko = ks * 32 + (lane >> 4) * 8;
      bf16x8 af[4], bfr[4];
#pragma unroll
      for (int i = 0; i < 4; ++i) {
        af[i] = *(const bf16x8*)&As[(wm * 64 + i * 16 + (lane & 15)) * 64 + ko];
        bfr[i] = *(const bf16x8*)&Bs[(wn * 64 + i * 16 + (lane & 15)) * 64 + ko];
      }
#pragma unroll
      for (int i = 0; i < 4; ++i)
#pragma unroll
        for (int j2 = 0; j2 < 4; ++j2)
          acc[i][j2] = __builtin_amdgcn_mfma_f32_16x16x32_bf16(af[i], bfr[j2], acc[i][j2], 0, 0, 0);
    }
    __syncthreads();
  }

  int rowBase = bm * 128 + wm * 64 + (lane >> 4) * 4;
  int colBase = bn * 128 + wn * 64 + (lane & 15);
#pragma unroll
  for (int i = 0; i < 4; ++i) {
#pragma unroll
    for (int j2 = 0; j2 < 4; ++j2) {
      int gn = colBase + j2 * 16;
      float bv = bias[gn];
#pragma unroll
      for (int r = 0; r < 4; ++r) {
        int gm = rowBase + i * 16 + r;
        Cout[(size_t)gm * Nn + gn] = acc[i][j2][r] + bv + (float)vin[(size_t)gm * Nn + gn];
      }
    }
  }
}

// ---------------- attention over 6 kv slabs (vo bf16) ----------------
__global__ __launch_bounds__(512)
void attn_fuse(const bf16_t* __restrict__ vo, bf16_t* __restrict__ fuse)
{
  int m = blockIdx.x;
  int h = threadIdx.x >> 6;
  int lane = threadIdx.x & 63;
  const size_t slab = (size_t)M_TOK * CDIM;
  const bf16_t* base = vo + (size_t)m * CDIM + h * 128;
  float q0 = (float)base[lane], q1 = (float)base[lane + 64];
  float kv0[6], kv1[6], sc[6];
#pragma unroll
  for (int k = 0; k < 6; ++k) {
    const bf16_t* kb = base + (size_t)(k + 1) * slab;
    kv0[k] = (float)kb[lane]; kv1[k] = (float)kb[lane + 64];
    sc[k] = q0 * kv0[k] + q1 * kv1[k];
  }
#pragma unroll
  for (int k = 0; k < 6; ++k) {
#pragma unroll
    for (int off = 32; off; off >>= 1) sc[k] += __shfl_xor(sc[k], off);
    sc[k] *= 0.03125f;  // C^-0.5
  }
  float mx = sc[0];
#pragma unroll
  for (int k = 1; k < 6; ++k) mx = fmaxf(mx, sc[k]);
  float e[6], se = 0.f;
#pragma unroll
  for (int k = 0; k < 6; ++k) { e[k] = expf(sc[k] - mx); se += e[k]; }
  float inv = 1.f / se;
  float f0 = 0.f, f1 = 0.f;
#pragma unroll
  for (int k = 0; k < 6; ++k) { float w = e[k] * inv; f0 += w * kv0[k]; f1 += w * kv1[k]; }
  bf16_t* o = fuse + (size_t)m * CDIM + h * 128;
  o[lane] = (bf16_t)f0;
  o[lane + 64] = (bf16_t)f1;
}

// ---------------- cosine per row ----------------
__global__ __launch_bounds__(256)
void cos_row(const float* __restrict__ vf, const float* __restrict__ teacher, float* __restrict__ cosv)
{
  int m = blockIdx.x;
  int tid = threadIdx.x;
  float4 a = ((const float4*)(vf + (size_t)m * CDIM))[tid];
  float4 b = ((const float4*)(teacher + (size_t)m * CDIM))[tid];
  float dot = a.x * b.x + a.y * b.y + a.z * b.z + a.w * b.w;
  float na = a.x * a.x + a.y * a.y + a.z * a.z + a.w * a.w;
  float nb = b.x * b.x + b.y * b.y + b.z * b.z + b.w * b.w;
  int lane = tid & 63, wv = tid >> 6;
#pragma unroll
  for (int off = 32; off; off >>= 1) {
    dot += __shfl_xor(dot, off); na += __shfl_xor(na, off); nb += __shfl_xor(nb, off);
  }
  __shared__ float red[12];
  if (lane == 0) { red[wv] = dot; red[4 + wv] = na; red[8 + wv] = nb; }
  __syncthreads();
  if (tid == 0) {
    float d = red[0] + red[1] + red[2] + red[3];
    float x = red[4] + red[5] + red[6] + red[7];
    float y = red[8] + red[9] + red[10] + red[11];
    float den = fmaxf(sqrtf(x), 1e-8f) * fmaxf(sqrtf(y), 1e-8f);
    cosv[m] = d / den;
  }
}

__global__ __launch_bounds__(256)
void final_reduce(const float* __restrict__ cosv, float* __restrict__ out)
{
  int tid = threadIdx.x;
  float s = 0.f;
  for (int i = tid; i < M_TOK; i += 256) s += cosv[i];
  int lane = tid & 63, wv = tid >> 6;
#pragma unroll
  for (int off = 32; off; off >>= 1) s += __shfl_xor(s, off);
  __shared__ float red[4];
  if (lane == 0) red[wv] = s;
  __syncthreads();
  if (tid == 0) out[0] = 1.f - (red[0] + red[1] + red[2] + red[3]) * (1.f / M_TOK);
}

extern "C" void kernel_launch(void* const* d_in, const int* in_sizes, int n_in,
                              void* d_out, int out_size, void* d_ws, size_t ws_size,
                              hipStream_t stream)
{
  (void)in_sizes; (void)n_in; (void)out_size;
  const float* all_features = (const float*)d_in[0];
  const float* teacher = (const float*)d_in[1];
  const float* ln_gamma = (const float*)d_in[2];
  const float* ln_beta = (const float*)d_in[3];
  const float* norm_w = (const float*)d_in[4];
  const float* input_w = (const float*)d_in[5];
  const float* input_b = (const float*)d_in[6];
  const float* output_w = (const float*)d_in[7];
  const float* output_b = (const float*)d_in[8];
  float* out = (float*)d_out;
  char* ws = (char*)d_ws;

  const size_t M = M_TOK, D = DDIM, C = CDIM;
  const size_t xnB = 8 * M * D;          // 67 MB fp8 (slab7 = raw layer24)
  const size_t wbB = 8 * C * D;          // 33.5 MB fp8 (norm_w[0..6] + input_w)
  const size_t owbB = C * C * 2;         // 2 MB bf16
  const size_t voB = 8 * M * C * 2;      // 33.5 MB bf16 (slab7 = vin)
  const size_t fuseB = M * C * 2;
  const size_t vfB = M * C * 4;
  const size_t cosB = M * 4;
  const size_t fastTotal = xnB + wbB + owbB + voB + fuseB + vfB + cosB;  // ~148 MB

  if (ws_size >= fastTotal) {
    u8* xn = (u8*)ws;
    u8* wb = (u8*)(ws + xnB);
    bf16_t* owb = (bf16_t*)(ws + xnB + wbB);
    bf16_t* vo = (bf16_t*)(ws + xnB + wbB + owbB);
    bf16_t* fuse = (bf16_t*)(ws + xnB + wbB + owbB + voB);
    float* vf = (float*)(ws + xnB + wbB + owbB + voB + fuseB);
    float* cosv = (float*)(ws + xnB + wbB + owbB + voB + fuseB + vfB);

    dim3 gp((unsigned)M, 8);
    prep<<<gp, 256, 0, stream>>>(all_features, ln_gamma, ln_beta, xn,
                                 norm_w, input_w, output_w, wb, owb);
    gemm256f8<<<256, 512, 0, stream>>>(xn, wb, vo, input_b,
                                       (int)M, (int)C, (int)D, 0, 32, 4);
    attn_fuse<<<(unsigned)M, 512, 0, stream>>>(vo, fuse);
    gemm_bt_epi<<<128, 256, 0, stream>>>(fuse, owb, vf, output_b, vo + (size_t)7 * M * C,
                                         (int)M, (int)C, (int)C, 8);
    cos_row<<<(unsigned)M, 256, 0, stream>>>(vf, teacher, cosv);
    final_reduce<<<1, 256, 0, stream>>>(cosv, out);
  } else {
    // SMALL-ws fallback: loop j, reuse one xn/wb slab (fp8).
    const size_t xn1B = M * D;
    const size_t wb1B = C * D;
    u8* xn1 = (u8*)ws;
    u8* wb1 = (u8*)(ws + xn1B);
    bf16_t* owb = (bf16_t*)(ws + xn1B + wb1B);
    bf16_t* vo = (bf16_t*)(ws + xn1B + wb1B + owbB);
    bf16_t* fuse = (bf16_t*)(ws + xn1B + wb1B + owbB + voB);
    float* vf = (float*)(ws + xn1B + wb1B + owbB + voB + fuseB);
    float* cosv = (float*)(ws + xn1B + wb1B + owbB + voB + fuseB + vfB);

    cvt_bf16<<<512, 256, 0, stream>>>(output_w, owb, (long)(C * C));
    for (int j = 0; j < 8; ++j) {
      const float* wsrc = (j < 7) ? (norm_w + (size_t)j * C * D) : input_w;
      cvt_fp8<<<2048, 256, 0, stream>>>(wsrc, wb1, (long)(C * D));
      dim3 g1((unsigned)M, 1);
      ln_convert<<<g1, 256, 0, stream>>>(all_features, ln_gamma, ln_beta, xn1, j, 0);
      gemm256f8<<<32, 512, 0, stream>>>(xn1, wb1, vo, input_b,
                                        (int)M, (int)C, (int)D, j, 32, 4);
    }
    attn_fuse<<<(unsigned)M, 512, 0, stream>>>(vo, fuse);
    gemm_bt_epi<<<128, 256, 0, stream>>>(fuse, owb, vf, output_b, vo + (size_t)7 * M * C,
                                         (int)M, (int)C, (int)C, 8);
    cos_row<<<(unsigned)M, 256, 0, stream>>>(vf, teacher, cosv);
    final_reduce<<<1, 256, 0, stream>>>(cosv, out);
  }
}

// Round 11
// 213.280 us; speedup vs baseline: 1.3708x; 1.1065x over previous
//
#include <hip/hip_runtime.h>
#include <cstdint>
#include <cstring>

#define M_TOK 2048   // BT*S
#define DDIM 4096
#define CDIM 1024
#define LTOT 25

typedef __bf16 bf16_t;
typedef __attribute__((ext_vector_type(8))) __bf16 bf16x8;
typedef __attribute__((ext_vector_type(4))) float f32x4;
typedef __attribute__((ext_vector_type(16))) float f32x16;
typedef __attribute__((ext_vector_type(8))) int i32x8;
typedef unsigned char u8;

__device__ __forceinline__ void gload16(const void* g, void* l) {
  __builtin_amdgcn_global_load_lds(
      (const __attribute__((address_space(1))) unsigned int*)g,
      (__attribute__((address_space(3))) unsigned int*)l, 16, 0, 0);
}

__device__ __forceinline__ unsigned int pk4_fp8(float x, float y, float z, float w) {
  int r = __builtin_amdgcn_cvt_pk_fp8_f32(x, y, 0, false);   // bytes 0,1
  r = __builtin_amdgcn_cvt_pk_fp8_f32(z, w, r, true);        // bytes 2,3
  return (unsigned int)r;
}

// ---------------- fp32 -> fp8 convert (small-ws path) ----------------
__global__ void cvt_fp8(const float* __restrict__ src, u8* __restrict__ dst, long n) {
  long stride = (long)gridDim.x * blockDim.x;
  for (long i = (long)blockIdx.x * blockDim.x + threadIdx.x; i * 8 < n; i += stride) {
    const float4* s4 = (const float4*)(src + i * 8);
    float4 a = s4[0], b = s4[1];
    uint2 pk;
    pk.x = pk4_fp8(a.x, a.y, a.z, a.w);
    pk.y = pk4_fp8(b.x, b.y, b.z, b.w);
    *(uint2*)(dst + i * 8) = pk;
  }
}

// ---------------- fp32 -> bf16 convert (owb, small-ws path) ----------------
__global__ void cvt_bf16(const float* __restrict__ src, bf16_t* __restrict__ dst, long n) {
  long stride = (long)gridDim.x * blockDim.x;
  for (long i = (long)blockIdx.x * blockDim.x + threadIdx.x; i * 8 < n; i += stride) {
    const float4* s4 = (const float4*)(src + i * 8);
    float4 a = s4[0], b = s4[1];
    bf16_t o[8] = {(bf16_t)a.x, (bf16_t)a.y, (bf16_t)a.z, (bf16_t)a.w,
                   (bf16_t)b.x, (bf16_t)b.y, (bf16_t)b.z, (bf16_t)b.w};
    uint4 pk;
    __builtin_memcpy(&pk, o, 16);
    *(uint4*)(dst + i * 8) = pk;
  }
}

// ---------------- LayerNorm + gather + fp8 convert (small-ws path) ----------------
__global__ __launch_bounds__(256)
void ln_convert(const float* __restrict__ af, const float* __restrict__ gamma,
                const float* __restrict__ beta, u8* __restrict__ xn,
                int jBase, int fuse7)
{
  int m = blockIdx.x;
  int jl = blockIdx.y;
  int j = jBase + jl;
  int layer = (j < 7) ? (24 - 4 * j) : 24;
  const float4* row4 = (const float4*)(af + ((size_t)m * LTOT + layer) * DDIM);
  int tid = threadIdx.x;
  float4 v[4];
  float s = 0.f, ss = 0.f;
#pragma unroll
  for (int i = 0; i < 4; ++i) {
    v[i] = row4[i * 256 + tid];
    s += v[i].x + v[i].y + v[i].z + v[i].w;
    ss += v[i].x * v[i].x + v[i].y * v[i].y + v[i].z * v[i].z + v[i].w * v[i].w;
  }
  int lane = tid & 63, wv = tid >> 6;
#pragma unroll
  for (int off = 32; off; off >>= 1) { s += __shfl_xor(s, off); ss += __shfl_xor(ss, off); }
  __shared__ float red[8];
  if (lane == 0) { red[wv] = s; red[4 + wv] = ss; }
  __syncthreads();
  s = red[0] + red[1] + red[2] + red[3];
  ss = red[4] + red[5] + red[6] + red[7];
  float mu = 0.f, rs = 1.f;
  if (j < 7) {
    mu = s * (1.f / DDIM);
    float var = ss * (1.f / DDIM) - mu * mu;
    rs = rsqrtf(var + 1e-5f);
  }
  if (fuse7 && jl == 0) {
    u8* o7 = xn + ((size_t)7 * M_TOK + m) * DDIM;
#pragma unroll
    for (int i = 0; i < 4; ++i)
      ((unsigned int*)o7)[i * 256 + tid] = pk4_fp8(v[i].x, v[i].y, v[i].z, v[i].w);
  }
  u8* orow = xn + ((size_t)jl * M_TOK + m) * DDIM;
  int jw = (j < 7) ? j : 0;
  const float4* g4 = (const float4*)(gamma + (size_t)jw * DDIM);
  const float4* b4 = (const float4*)(beta + (size_t)jw * DDIM);
#pragma unroll
  for (int i = 0; i < 4; ++i) {
    float4 x = v[i];
    float4 ov;
    if (j < 7) {
      float4 g = g4[i * 256 + tid], bb = b4[i * 256 + tid];
      ov.x = (x.x - mu) * rs * g.x + bb.x;
      ov.y = (x.y - mu) * rs * g.y + bb.y;
      ov.z = (x.z - mu) * rs * g.z + bb.z;
      ov.w = (x.w - mu) * rs * g.w + bb.w;
    } else ov = x;
    ((unsigned int*)orow)[i * 256 + tid] = pk4_fp8(ov.x, ov.y, ov.z, ov.w);
  }
}

// ---------------- fused prep: LN->fp8 slabs (y<7, slab7 in y==0) + weight cvt (y==7) --
__global__ __launch_bounds__(256)
void prep(const float* __restrict__ af, const float* __restrict__ gamma,
          const float* __restrict__ beta, u8* __restrict__ xn,
          const float* __restrict__ norm_w, const float* __restrict__ input_w,
          const float* __restrict__ output_w, u8* __restrict__ wb8,
          bf16_t* __restrict__ owb)
{
  int tid = threadIdx.x;
  if (blockIdx.y == 7) {
    const long NW7 = (long)7 * CDIM * DDIM;
    const long NWI = (long)8 * CDIM * DDIM;
    const long TOT = NWI + (long)CDIM * CDIM;
    long stride = (long)gridDim.x * blockDim.x;
    for (long i = (long)blockIdx.x * blockDim.x + tid; i * 8 < TOT; i += stride) {
      long e = i * 8;
      const float* sp;
      if (e < NW7)      sp = norm_w + e;
      else if (e < NWI) sp = input_w + (e - NW7);
      else              sp = output_w + (e - NWI);
      const float4* s4 = (const float4*)sp;
      float4 a = s4[0], b = s4[1];
      if (e < NWI) {
        uint2 pk;
        pk.x = pk4_fp8(a.x, a.y, a.z, a.w);
        pk.y = pk4_fp8(b.x, b.y, b.z, b.w);
        *(uint2*)(wb8 + e) = pk;
      } else {
        bf16_t o[8] = {(bf16_t)a.x, (bf16_t)a.y, (bf16_t)a.z, (bf16_t)a.w,
                       (bf16_t)b.x, (bf16_t)b.y, (bf16_t)b.z, (bf16_t)b.w};
        uint4 pk;
        __builtin_memcpy(&pk, o, 16);
        *(uint4*)(owb + (e - NWI)) = pk;
      }
    }
    return;
  }
  int m = blockIdx.x;
  int jl = blockIdx.y;
  int layer = 24 - 4 * jl;
  const float4* row4 = (const float4*)(af + ((size_t)m * LTOT + layer) * DDIM);
  float4 v[4];
  float s = 0.f, ss = 0.f;
#pragma unroll
  for (int i = 0; i < 4; ++i) {
    v[i] = row4[i * 256 + tid];
    s += v[i].x + v[i].y + v[i].z + v[i].w;
    ss += v[i].x * v[i].x + v[i].y * v[i].y + v[i].z * v[i].z + v[i].w * v[i].w;
  }
  int lane = tid & 63, wv = tid >> 6;
#pragma unroll
  for (int off = 32; off; off >>= 1) { s += __shfl_xor(s, off); ss += __shfl_xor(ss, off); }
  __shared__ float red[8];
  if (lane == 0) { red[wv] = s; red[4 + wv] = ss; }
  __syncthreads();
  s = red[0] + red[1] + red[2] + red[3];
  ss = red[4] + red[5] + red[6] + red[7];
  float mu = s * (1.f / DDIM);
  float var = ss * (1.f / DDIM) - mu * mu;
  float rs = rsqrtf(var + 1e-5f);
  if (jl == 0) {
    u8* o7 = xn + ((size_t)7 * M_TOK + m) * DDIM;
#pragma unroll
    for (int i = 0; i < 4; ++i)
      ((unsigned int*)o7)[i * 256 + tid] = pk4_fp8(v[i].x, v[i].y, v[i].z, v[i].w);
  }
  u8* orow = xn + ((size_t)jl * M_TOK + m) * DDIM;
  const float4* g4 = (const float4*)(gamma + (size_t)jl * DDIM);
  const float4* b4 = (const float4*)(beta + (size_t)jl * DDIM);
#pragma unroll
  for (int i = 0; i < 4; ++i) {
    float4 x = v[i];
    float4 g = g4[i * 256 + tid], bb = b4[i * 256 + tid];
    float4 ov;
    ov.x = (x.x - mu) * rs * g.x + bb.x;
    ov.y = (x.y - mu) * rs * g.y + bb.y;
    ov.z = (x.z - mu) * rs * g.z + bb.z;
    ov.w = (x.w - mu) * rs * g.w + bb.w;
    ((unsigned int*)orow)[i * 256 + tid] = pk4_fp8(ov.x, ov.y, ov.z, ov.w);
  }
}

// ------ 256x256-tile MX-fp8 batched B^T GEMM (scale=1.0): ring-4, 3-ahead staging --
// C[jg][m][n] = bf16( sum_k A[jl][m][k]*B[jl][n][k] (+bias) ), A,B fp8 e4m3.
// mfma_scale_f32_32x32x64_f8f6f4, cbsz=blgp=0 (fp8), scale bytes = 127 (=2^0).
// 512 threads = 8 waves (2 wm x 4 wn); per-wave output 128x64 = 4x2 blocks of 32².
// BK=64 = one MFMA K-step. Staging/LDS/swizzle/vmcnt identical to round 10:
// ring-4 x (A 16 KB + B 16 KB); tile t staged during t-3; ONE vmcnt+barrier/tile.
// A/B frag: row=lane&31, k=(lane>>5)*32+e (dword d = k bytes d*4..d*4+3) —
// doubling pattern of the HW-verified fp8 16x16x32 layout (round 10).
// C/D: col=lane&31, row=(reg&3)+8*(reg>>2)+4*(lane>>5) — verified in round 7.
__global__ __launch_bounds__(512, 2)
void gemm256mx(const u8* __restrict__ A, const u8* __restrict__ B,
               bf16_t* __restrict__ Cout, const float* __restrict__ bias,
               int Mm, int Nn, int Kk, int jBase, int tilesPerJ, int tilesN)
{
  __shared__ __align__(16) u8 smem[131072];   // [0,64K) A ring, [64K,128K) B ring
  int nb = gridDim.x;
  int bid = blockIdx.x;
  if ((nb & 7) == 0) { int cpx = nb >> 3; bid = (bid & 7) * cpx + (bid >> 3); }  // XCD swizzle
  int jl = bid / tilesPerJ;
  int t0 = bid % tilesPerJ;
  int bm = t0 / tilesN, bn = t0 % tilesN;
  int jg = jBase + jl;

  const u8* Aj = A + (size_t)jl * Mm * Kk + (size_t)bm * 256 * Kk;
  const u8* Bj = B + (size_t)jl * Nn * Kk + (size_t)bn * 256 * Kk;

  int tid = threadIdx.x;
  int lane = tid & 63, wid = tid >> 6;
  int wm = wid >> 2, wn = wid & 3;

  // staging (identical to round 10): rows 128h + wid*16 + (lane>>2); pair = lane&3
  int srow = wid * 16 + (lane >> 2);
  int spre = ((lane & 3) ^ ((lane >> 3) & 3)) * 16;
  const u8* Ast = Aj + (size_t)srow * Kk + spre;
  const u8* Bst = Bj + (size_t)srow * Kk + spre;

  // read addressing: row r = blk*32 + (lane&31); lane's k bytes (lane>>5)*32+0..31
  // = global 8B-slots (lane>>5)*4+q, q=0..3; stored slot = s ^ (((r>>1)&3)<<1)
  int l31 = lane & 31;
  int lh = lane >> 5;
  int rsw = ((l31 >> 1) & 3) << 1;
  int so[4];
#pragma unroll
  for (int q = 0; q < 4; ++q) so[q] = ((lh * 4 + q) ^ rsw) * 8;

  int NT = Kk >> 6;
  f32x16 acc[4][2] = {};

#define STAGE4(tt_)                                                              \
  { gload16(Ast + (size_t)(tt_) * 64,                 &smem[((tt_) & 3) * 16384 + wid * 1024]); \
    gload16(Ast + (size_t)128 * Kk + (size_t)(tt_) * 64, &smem[((tt_) & 3) * 16384 + 8192 + wid * 1024]); \
    gload16(Bst + (size_t)(tt_) * 64,                 &smem[65536 + ((tt_) & 3) * 16384 + wid * 1024]); \
    gload16(Bst + (size_t)128 * Kk + (size_t)(tt_) * 64, &smem[65536 + ((tt_) & 3) * 16384 + 8192 + wid * 1024]); }

#define BAR() asm volatile("s_barrier" ::: "memory")

  STAGE4(0);
  if (NT > 1) STAGE4(1);
  if (NT > 2) STAGE4(2);
  if (NT > 2)      asm volatile("s_waitcnt vmcnt(8)" ::: "memory");
  else if (NT > 1) asm volatile("s_waitcnt vmcnt(4)" ::: "memory");
  else             asm volatile("s_waitcnt vmcnt(0)" ::: "memory");
  BAR();

#pragma unroll 1
  for (int t = 0; t < NT; ++t) {
    const u8* Ab = &smem[(t & 3) * 16384 + wm * 8192];      // wave's 128 rows of A
    const u8* Bb = &smem[65536 + (t & 3) * 16384 + wn * 4096];  // wave's 64 rows of B
    i32x8 Afr[4], Bfr[2];
#pragma unroll
    for (int ib = 0; ib < 4; ++ib) {
      const u8* rp = Ab + (ib * 32 + l31) * 64;
#pragma unroll
      for (int q = 0; q < 4; ++q) {
        long long v = *(const long long*)(rp + so[q]);
        Afr[ib][2 * q] = (int)v;
        Afr[ib][2 * q + 1] = (int)(v >> 32);
      }
    }
#pragma unroll
    for (int jb = 0; jb < 2; ++jb) {
      const u8* rp = Bb + (jb * 32 + l31) * 64;
#pragma unroll
      for (int q = 0; q < 4; ++q) {
        long long v = *(const long long*)(rp + so[q]);
        Bfr[jb][2 * q] = (int)v;
        Bfr[jb][2 * q + 1] = (int)(v >> 32);
      }
    }
    if (t + 3 < NT) STAGE4(t + 3);
    __builtin_amdgcn_s_setprio(1);
#pragma unroll
    for (int ib = 0; ib < 4; ++ib)
#pragma unroll
      for (int jb = 0; jb < 2; ++jb)
        acc[ib][jb] = __builtin_amdgcn_mfma_scale_f32_32x32x64_f8f6f4(
            Afr[ib], Bfr[jb], acc[ib][jb], 0, 0, 0, 127, 0, 127);
    __builtin_amdgcn_s_setprio(0);
    if (t + 1 < NT) {
      asm volatile("s_waitcnt lgkmcnt(0)" ::: "memory");
      if (t + 3 < NT)      asm volatile("s_waitcnt vmcnt(8)" ::: "memory");
      else if (t + 2 < NT) asm volatile("s_waitcnt vmcnt(4)" ::: "memory");
      else                 asm volatile("s_waitcnt vmcnt(0)" ::: "memory");
      BAR();
    }
  }
#undef STAGE4
#undef BAR

  // C/D: col=lane&31, row=(reg&3)+8*(reg>>2)+4*(lane>>5)
  int col0 = bn * 256 + wn * 64 + l31;
  int row0 = bm * 256 + wm * 128 + lh * 4;
  bf16_t* Cj = Cout + (size_t)jg * Mm * Nn;
  float bv0 = (jg == 7) ? bias[col0] : 0.f;
  float bv1 = (jg == 7) ? bias[col0 + 32] : 0.f;
#pragma unroll
  for (int ib = 0; ib < 4; ++ib) {
#pragma unroll
    for (int jb = 0; jb < 2; ++jb) {
      float bv = jb ? bv1 : bv0;
      int gc = col0 + jb * 32;
#pragma unroll
      for (int reg = 0; reg < 16; ++reg) {
        int gr = row0 + ib * 32 + (reg & 3) + 8 * (reg >> 2);
        Cj[(size_t)gr * Nn + gc] = (bf16_t)(acc[ib][jb][reg] + bv);
      }
    }
  }
}

// ---------------- 128x128-tile bf16 GEMM for the output projection ----------------
__global__ __launch_bounds__(256)
void gemm_bt_epi(const bf16_t* __restrict__ A, const bf16_t* __restrict__ B,
                 float* __restrict__ Cout, const float* __restrict__ bias,
                 const bf16_t* __restrict__ vin, int Mm, int Nn, int Kk, int tilesN)
{
  __shared__ bf16_t As[128 * 64];
  __shared__ bf16_t Bs[128 * 64];
  int bid = blockIdx.x;
  int bm = bid / tilesN, bn = bid % tilesN;
  const bf16_t* Aj = A + (size_t)bm * 128 * Kk;
  const bf16_t* Bj = B + (size_t)bn * 128 * Kk;

  int tid = threadIdx.x;
  int lane = tid & 63, wv = tid >> 6;
  int wm = wv >> 1, wn = wv & 1;

  f32x4 acc[4][4] = {};

  int srow = wv * 32 + (lane >> 3);
  int scol = (lane & 7) * 8;
  const bf16_t* Ag = Aj + (size_t)srow * Kk + scol;
  const bf16_t* Bg = Bj + (size_t)srow * Kk + scol;

  for (int kt = 0; kt < Kk; kt += 64) {
#pragma unroll
    for (int c = 0; c < 4; ++c) {
      gload16(Ag + kt + (size_t)(c * 8) * Kk, &As[(wv * 32 + c * 8) * 64]);
      gload16(Bg + kt + (size_t)(c * 8) * Kk, &Bs[(wv * 32 + c * 8) * 64]);
    }
    __syncthreads();
#pragma unroll
    for (int ks = 0; ks < 2; ++ks) {
      int ko = ks * 32 + (lane >> 4) * 8;
      bf16x8 af[4], bfr[4];
#pragma unroll
      for (int i = 0; i < 4; ++i) {
        af[i] = *(const bf16x8*)&As[(wm * 64 + i * 16 + (lane & 15)) * 64 + ko];
        bfr[i] = *(const bf16x8*)&Bs[(wn * 64 + i * 16 + (lane & 15)) * 64 + ko];
      }
#pragma unroll
      for (int i = 0; i < 4; ++i)
#pragma unroll
        for (int j2 = 0; j2 < 4; ++j2)
          acc[i][j2] = __builtin_amdgcn_mfma_f32_16x16x32_bf16(af[i], bfr[j2], acc[i][j2], 0, 0, 0);
    }
    __syncthreads();
  }

  int rowBase = bm * 128 + wm * 64 + (lane >> 4) * 4;
  int colBase = bn * 128 + wn * 64 + (lane & 15);
#pragma unroll
  for (int i = 0; i < 4; ++i) {
#pragma unroll
    for (int j2 = 0; j2 < 4; ++j2) {
      int gn = colBase + j2 * 16;
      float bv = bias[gn];
#pragma unroll
      for (int r = 0; r < 4; ++r) {
        int gm = rowBase + i * 16 + r;
        Cout[(size_t)gm * Nn + gn] = acc[i][j2][r] + bv + (float)vin[(size_t)gm * Nn + gn];
      }
    }
  }
}

// ---------------- attention over 6 kv slabs (vo bf16) ----------------
__global__ __launch_bounds__(512)
void attn_fuse(const bf16_t* __restrict__ vo, bf16_t* __restrict__ fuse)
{
  int m = blockIdx.x;
  int h = threadIdx.x >> 6;
  int lane = threadIdx.x & 63;
  const size_t slab = (size_t)M_TOK * CDIM;
  const bf16_t* base = vo + (size_t)m * CDIM + h * 128;
  float q0 = (float)base[lane], q1 = (float)base[lane + 64];
  float kv0[6], kv1[6], sc[6];
#pragma unroll
  for (int k = 0; k < 6; ++k) {
    const bf16_t* kb = base + (size_t)(k + 1) * slab;
    kv0[k] = (float)kb[lane]; kv1[k] = (float)kb[lane + 64];
    sc[k] = q0 * kv0[k] + q1 * kv1[k];
  }
#pragma unroll
  for (int k = 0; k < 6; ++k) {
#pragma unroll
    for (int off = 32; off; off >>= 1) sc[k] += __shfl_xor(sc[k], off);
    sc[k] *= 0.03125f;  // C^-0.5
  }
  float mx = sc[0];
#pragma unroll
  for (int k = 1; k < 6; ++k) mx = fmaxf(mx, sc[k]);
  float e[6], se = 0.f;
#pragma unroll
  for (int k = 0; k < 6; ++k) { e[k] = expf(sc[k] - mx); se += e[k]; }
  float inv = 1.f / se;
  float f0 = 0.f, f1 = 0.f;
#pragma unroll
  for (int k = 0; k < 6; ++k) { float w = e[k] * inv; f0 += w * kv0[k]; f1 += w * kv1[k]; }
  bf16_t* o = fuse + (size_t)m * CDIM + h * 128;
  o[lane] = (bf16_t)f0;
  o[lane + 64] = (bf16_t)f1;
}

// ---------------- cosine per row ----------------
__global__ __launch_bounds__(256)
void cos_row(const float* __restrict__ vf, const float* __restrict__ teacher, float* __restrict__ cosv)
{
  int m = blockIdx.x;
  int tid = threadIdx.x;
  float4 a = ((const float4*)(vf + (size_t)m * CDIM))[tid];
  float4 b = ((const float4*)(teacher + (size_t)m * CDIM))[tid];
  float dot = a.x * b.x + a.y * b.y + a.z * b.z + a.w * b.w;
  float na = a.x * a.x + a.y * a.y + a.z * a.z + a.w * a.w;
  float nb = b.x * b.x + b.y * b.y + b.z * b.z + b.w * b.w;
  int lane = tid & 63, wv = tid >> 6;
#pragma unroll
  for (int off = 32; off; off >>= 1) {
    dot += __shfl_xor(dot, off); na += __shfl_xor(na, off); nb += __shfl_xor(nb, off);
  }
  __shared__ float red[12];
  if (lane == 0) { red[wv] = dot; red[4 + wv] = na; red[8 + wv] = nb; }
  __syncthreads();
  if (tid == 0) {
    float d = red[0] + red[1] + red[2] + red[3];
    float x = red[4] + red[5] + red[6] + red[7];
    float y = red[8] + red[9] + red[10] + red[11];
    float den = fmaxf(sqrtf(x), 1e-8f) * fmaxf(sqrtf(y), 1e-8f);
    cosv[m] = d / den;
  }
}

__global__ __launch_bounds__(256)
void final_reduce(const float* __restrict__ cosv, float* __restrict__ out)
{
  int tid = threadIdx.x;
  float s = 0.f;
  for (int i = tid; i < M_TOK; i += 256) s += cosv[i];
  int lane = tid & 63, wv = tid >> 6;
#pragma unroll
  for (int off = 32; off; off >>= 1) s += __shfl_xor(s, off);
  __shared__ float red[4];
  if (lane == 0) red[wv] = s;
  __syncthreads();
  if (tid == 0) out[0] = 1.f - (red[0] + red[1] + red[2] + red[3]) * (1.f / M_TOK);
}

extern "C" void kernel_launch(void* const* d_in, const int* in_sizes, int n_in,
                              void* d_out, int out_size, void* d_ws, size_t ws_size,
                              hipStream_t stream)
{
  (void)in_sizes; (void)n_in; (void)out_size;
  const float* all_features = (const float*)d_in[0];
  const float* teacher = (const float*)d_in[1];
  const float* ln_gamma = (const float*)d_in[2];
  const float* ln_beta = (const float*)d_in[3];
  const float* norm_w = (const float*)d_in[4];
  const float* input_w = (const float*)d_in[5];
  const float* input_b = (const float*)d_in[6];
  const float* output_w = (const float*)d_in[7];
  const float* output_b = (const float*)d_in[8];
  float* out = (float*)d_out;
  char* ws = (char*)d_ws;

  const size_t M = M_TOK, D = DDIM, C = CDIM;
  const size_t xnB = 8 * M * D;          // 67 MB fp8 (slab7 = raw layer24)
  const size_t wbB = 8 * C * D;          // 33.5 MB fp8 (norm_w[0..6] + input_w)
  const size_t owbB = C * C * 2;         // 2 MB bf16
  const size_t voB = 8 * M * C * 2;      // 33.5 MB bf16 (slab7 = vin)
  const size_t fuseB = M * C * 2;
  const size_t vfB = M * C * 4;
  const size_t cosB = M * 4;
  const size_t fastTotal = xnB + wbB + owbB + voB + fuseB + vfB + cosB;  // ~148 MB

  if (ws_size >= fastTotal) {
    u8* xn = (u8*)ws;
    u8* wb = (u8*)(ws + xnB);
    bf16_t* owb = (bf16_t*)(ws + xnB + wbB);
    bf16_t* vo = (bf16_t*)(ws + xnB + wbB + owbB);
    bf16_t* fuse = (bf16_t*)(ws + xnB + wbB + owbB + voB);
    float* vf = (float*)(ws + xnB + wbB + owbB + voB + fuseB);
    float* cosv = (float*)(ws + xnB + wbB + owbB + voB + fuseB + vfB);

    dim3 gp((unsigned)M, 8);
    prep<<<gp, 256, 0, stream>>>(all_features, ln_gamma, ln_beta, xn,
                                 norm_w, input_w, output_w, wb, owb);
    gemm256mx<<<256, 512, 0, stream>>>(xn, wb, vo, input_b,
                                       (int)M, (int)C, (int)D, 0, 32, 4);
    attn_fuse<<<(unsigned)M, 512, 0, stream>>>(vo, fuse);
    gemm_bt_epi<<<128, 256, 0, stream>>>(fuse, owb, vf, output_b, vo + (size_t)7 * M * C,
                                         (int)M, (int)C, (int)C, 8);
    cos_row<<<(unsigned)M, 256, 0, stream>>>(vf, teacher, cosv);
    final_reduce<<<1, 256, 0, stream>>>(cosv, out);
  } else {
    // SMALL-ws fallback: loop j, reuse one xn/wb slab (fp8).
    const size_t xn1B = M * D;
    const size_t wb1B = C * D;
    u8* xn1 = (u8*)ws;
    u8* wb1 = (u8*)(ws + xn1B);
    bf16_t* owb = (bf16_t*)(ws + xn1B + wb1B);
    bf16_t* vo = (bf16_t*)(ws + xn1B + wb1B + owbB);
    bf16_t* fuse = (bf16_t*)(ws + xn1B + wb1B + owbB + voB);
    float* vf = (float*)(ws + xn1B + wb1B + owbB + voB + fuseB);
    float* cosv = (float*)(ws + xn1B + wb1B + owbB + voB + fuseB + vfB);

    cvt_bf16<<<512, 256, 0, stream>>>(output_w, owb, (long)(C * C));
    for (int j = 0; j < 8; ++j) {
      const float* wsrc = (j < 7) ? (norm_w + (size_t)j * C * D) : input_w;
      cvt_fp8<<<2048, 256, 0, stream>>>(wsrc, wb1, (long)(C * D));
      dim3 g1((unsigned)M, 1);
      ln_convert<<<g1, 256, 0, stream>>>(all_features, ln_gamma, ln_beta, xn1, j, 0);
      gemm256mx<<<32, 512, 0, stream>>>(xn1, wb1, vo, input_b,
                                        (int)M, (int)C, (int)D, j, 32, 4);
    }
    attn_fuse<<<(unsigned)M, 512, 0, stream>>>(vo, fuse);
    gemm_bt_epi<<<128, 256, 0, stream>>>(fuse, owb, vf, output_b, vo + (size_t)7 * M * C,
                                         (int)M, (int)C, (int)C, 8);
    cos_row<<<(unsigned)M, 256, 0, stream>>>(vf, teacher, cosv);
    final_reduce<<<1, 256, 0, stream>>>(cosv, out);
  }
}

// Round 12
// 209.587 us; speedup vs baseline: 1.3950x; 1.0176x over previous
//
#include <hip/hip_runtime.h>
#include <cstdint>
#include <cstring>

#define M_TOK 2048   // BT*S
#define DDIM 4096
#define CDIM 1024
#define LTOT 25

typedef __bf16 bf16_t;
typedef __attribute__((ext_vector_type(8))) __bf16 bf16x8;
typedef __attribute__((ext_vector_type(4))) float f32x4;
typedef __attribute__((ext_vector_type(16))) float f32x16;
typedef __attribute__((ext_vector_type(8))) int i32x8;
typedef __attribute__((ext_vector_type(4))) unsigned int u32x4;
typedef unsigned char u8;

__device__ __forceinline__ void gload16(const void* g, void* l) {
  __builtin_amdgcn_global_load_lds(
      (const __attribute__((address_space(1))) unsigned int*)g,
      (__attribute__((address_space(3))) unsigned int*)l, 16, 0, 0);
}

__device__ __forceinline__ unsigned int pk4_fp8(float x, float y, float z, float w) {
  int r = __builtin_amdgcn_cvt_pk_fp8_f32(x, y, 0, false);   // bytes 0,1
  r = __builtin_amdgcn_cvt_pk_fp8_f32(z, w, r, true);        // bytes 2,3
  return (unsigned int)r;
}

// ---------------- fp32 -> fp8 convert (small-ws path) ----------------
__global__ void cvt_fp8(const float* __restrict__ src, u8* __restrict__ dst, long n) {
  long stride = (long)gridDim.x * blockDim.x;
  for (long i = (long)blockIdx.x * blockDim.x + threadIdx.x; i * 8 < n; i += stride) {
    const float4* s4 = (const float4*)(src + i * 8);
    float4 a = s4[0], b = s4[1];
    uint2 pk;
    pk.x = pk4_fp8(a.x, a.y, a.z, a.w);
    pk.y = pk4_fp8(b.x, b.y, b.z, b.w);
    *(uint2*)(dst + i * 8) = pk;
  }
}

// ---------------- fp32 -> bf16 convert (owb, small-ws path) ----------------
__global__ void cvt_bf16(const float* __restrict__ src, bf16_t* __restrict__ dst, long n) {
  long stride = (long)gridDim.x * blockDim.x;
  for (long i = (long)blockIdx.x * blockDim.x + threadIdx.x; i * 8 < n; i += stride) {
    const float4* s4 = (const float4*)(src + i * 8);
    float4 a = s4[0], b = s4[1];
    bf16_t o[8] = {(bf16_t)a.x, (bf16_t)a.y, (bf16_t)a.z, (bf16_t)a.w,
                   (bf16_t)b.x, (bf16_t)b.y, (bf16_t)b.z, (bf16_t)b.w};
    uint4 pk;
    __builtin_memcpy(&pk, o, 16);
    *(uint4*)(dst + i * 8) = pk;
  }
}

// ---------------- LayerNorm + gather + fp8 convert (small-ws path) ----------------
__global__ __launch_bounds__(256)
void ln_convert(const float* __restrict__ af, const float* __restrict__ gamma,
                const float* __restrict__ beta, u8* __restrict__ xn,
                int jBase, int fuse7)
{
  int m = blockIdx.x;
  int jl = blockIdx.y;
  int j = jBase + jl;
  int layer = (j < 7) ? (24 - 4 * j) : 24;
  const float4* row4 = (const float4*)(af + ((size_t)m * LTOT + layer) * DDIM);
  int tid = threadIdx.x;
  float4 v[4];
  float s = 0.f, ss = 0.f;
#pragma unroll
  for (int i = 0; i < 4; ++i) {
    v[i] = row4[i * 256 + tid];
    s += v[i].x + v[i].y + v[i].z + v[i].w;
    ss += v[i].x * v[i].x + v[i].y * v[i].y + v[i].z * v[i].z + v[i].w * v[i].w;
  }
  int lane = tid & 63, wv = tid >> 6;
#pragma unroll
  for (int off = 32; off; off >>= 1) { s += __shfl_xor(s, off); ss += __shfl_xor(ss, off); }
  __shared__ float red[8];
  if (lane == 0) { red[wv] = s; red[4 + wv] = ss; }
  __syncthreads();
  s = red[0] + red[1] + red[2] + red[3];
  ss = red[4] + red[5] + red[6] + red[7];
  float mu = 0.f, rs = 1.f;
  if (j < 7) {
    mu = s * (1.f / DDIM);
    float var = ss * (1.f / DDIM) - mu * mu;
    rs = rsqrtf(var + 1e-5f);
  }
  if (fuse7 && jl == 0) {
    u8* o7 = xn + ((size_t)7 * M_TOK + m) * DDIM;
#pragma unroll
    for (int i = 0; i < 4; ++i)
      ((unsigned int*)o7)[i * 256 + tid] = pk4_fp8(v[i].x, v[i].y, v[i].z, v[i].w);
  }
  u8* orow = xn + ((size_t)jl * M_TOK + m) * DDIM;
  int jw = (j < 7) ? j : 0;
  const float4* g4 = (const float4*)(gamma + (size_t)jw * DDIM);
  const float4* b4 = (const float4*)(beta + (size_t)jw * DDIM);
#pragma unroll
  for (int i = 0; i < 4; ++i) {
    float4 x = v[i];
    float4 ov;
    if (j < 7) {
      float4 g = g4[i * 256 + tid], bb = b4[i * 256 + tid];
      ov.x = (x.x - mu) * rs * g.x + bb.x;
      ov.y = (x.y - mu) * rs * g.y + bb.y;
      ov.z = (x.z - mu) * rs * g.z + bb.z;
      ov.w = (x.w - mu) * rs * g.w + bb.w;
    } else ov = x;
    ((unsigned int*)orow)[i * 256 + tid] = pk4_fp8(ov.x, ov.y, ov.z, ov.w);
  }
}

// ---------------- fused prep: LN->fp8 slabs (y<7, slab7 in y==0) + weight cvt (y==7) --
__global__ __launch_bounds__(256)
void prep(const float* __restrict__ af, const float* __restrict__ gamma,
          const float* __restrict__ beta, u8* __restrict__ xn,
          const float* __restrict__ norm_w, const float* __restrict__ input_w,
          const float* __restrict__ output_w, u8* __restrict__ wb8,
          bf16_t* __restrict__ owb)
{
  int tid = threadIdx.x;
  if (blockIdx.y == 7) {
    const long NW7 = (long)7 * CDIM * DDIM;
    const long NWI = (long)8 * CDIM * DDIM;
    const long TOT = NWI + (long)CDIM * CDIM;
    long stride = (long)gridDim.x * blockDim.x;
    for (long i = (long)blockIdx.x * blockDim.x + tid; i * 8 < TOT; i += stride) {
      long e = i * 8;
      const float* sp;
      if (e < NW7)      sp = norm_w + e;
      else if (e < NWI) sp = input_w + (e - NW7);
      else              sp = output_w + (e - NWI);
      const float4* s4 = (const float4*)sp;
      float4 a = s4[0], b = s4[1];
      if (e < NWI) {
        uint2 pk;
        pk.x = pk4_fp8(a.x, a.y, a.z, a.w);
        pk.y = pk4_fp8(b.x, b.y, b.z, b.w);
        *(uint2*)(wb8 + e) = pk;
      } else {
        bf16_t o[8] = {(bf16_t)a.x, (bf16_t)a.y, (bf16_t)a.z, (bf16_t)a.w,
                       (bf16_t)b.x, (bf16_t)b.y, (bf16_t)b.z, (bf16_t)b.w};
        uint4 pk;
        __builtin_memcpy(&pk, o, 16);
        *(uint4*)(owb + (e - NWI)) = pk;
      }
    }
    return;
  }
  int m = blockIdx.x;
  int jl = blockIdx.y;
  int layer = 24 - 4 * jl;
  const float4* row4 = (const float4*)(af + ((size_t)m * LTOT + layer) * DDIM);
  float4 v[4];
  float s = 0.f, ss = 0.f;
#pragma unroll
  for (int i = 0; i < 4; ++i) {
    v[i] = row4[i * 256 + tid];
    s += v[i].x + v[i].y + v[i].z + v[i].w;
    ss += v[i].x * v[i].x + v[i].y * v[i].y + v[i].z * v[i].z + v[i].w * v[i].w;
  }
  int lane = tid & 63, wv = tid >> 6;
#pragma unroll
  for (int off = 32; off; off >>= 1) { s += __shfl_xor(s, off); ss += __shfl_xor(ss, off); }
  __shared__ float red[8];
  if (lane == 0) { red[wv] = s; red[4 + wv] = ss; }
  __syncthreads();
  s = red[0] + red[1] + red[2] + red[3];
  ss = red[4] + red[5] + red[6] + red[7];
  float mu = s * (1.f / DDIM);
  float var = ss * (1.f / DDIM) - mu * mu;
  float rs = rsqrtf(var + 1e-5f);
  if (jl == 0) {
    u8* o7 = xn + ((size_t)7 * M_TOK + m) * DDIM;
#pragma unroll
    for (int i = 0; i < 4; ++i)
      ((unsigned int*)o7)[i * 256 + tid] = pk4_fp8(v[i].x, v[i].y, v[i].z, v[i].w);
  }
  u8* orow = xn + ((size_t)jl * M_TOK + m) * DDIM;
  const float4* g4 = (const float4*)(gamma + (size_t)jl * DDIM);
  const float4* b4 = (const float4*)(beta + (size_t)jl * DDIM);
#pragma unroll
  for (int i = 0; i < 4; ++i) {
    float4 x = v[i];
    float4 g = g4[i * 256 + tid], bb = b4[i * 256 + tid];
    float4 ov;
    ov.x = (x.x - mu) * rs * g.x + bb.x;
    ov.y = (x.y - mu) * rs * g.y + bb.y;
    ov.z = (x.z - mu) * rs * g.z + bb.z;
    ov.w = (x.w - mu) * rs * g.w + bb.w;
    ((unsigned int*)orow)[i * 256 + tid] = pk4_fp8(ov.x, ov.y, ov.z, ov.w);
  }
}

// ------ 256x256-tile MX-fp8 batched B^T GEMM: fragment-major LDS, ring-4 ------
// C[jg][m][n] = bf16( sum_k A[jl][m][k]*B[jl][n][k] (+bias) ), A,B fp8 e4m3.
// mfma_scale_f32_32x32x64_f8f6f4, scale bytes = 127 (=2^0). BK=64 = 1 K-step.
// LDS layout (per 8 KB chunk = 128 panel rows x 64 k-bytes), fragment-major:
//   byte = ib*2048 + lh*1024 + ( l31*32 | ((h ^ ((l31>>2)&1))<<4) )
//   for local row = ib*32+l31, k-half lh, 16B-half h. Lane's 32 k-bytes are the
//   contiguous pair {l31*32, l31*32+16} (halves swapped when (l31>>2)&1).
// Reads: 2 x ds_read_b128 per 32-block; 8-lane slot walk covers all 8 bank-quads
// -> bank-floor, zero conflicts. Staging: linear gload16 dest (slot S=wid*64+lane),
// per-lane source precomputed from S inverse mapping (both-sides involution).
// Schedule identical to round 11: ring-4, 3-tiles-ahead, ONE vmcnt+barrier/tile.
// C/D: col=lane&31, row=(reg&3)+8*(reg>>2)+4*(lane>>5)  [HW-verified r7/r11]
__global__ __launch_bounds__(512, 2)
void gemm256mx(const u8* __restrict__ A, const u8* __restrict__ B,
               bf16_t* __restrict__ Cout, const float* __restrict__ bias,
               int Mm, int Nn, int Kk, int jBase, int tilesPerJ, int tilesN)
{
  __shared__ __align__(16) u8 smem[131072];   // [0,64K) A ring, [64K,128K) B ring
  int nb = gridDim.x;
  int bid = blockIdx.x;
  if ((nb & 7) == 0) { int cpx = nb >> 3; bid = (bid & 7) * cpx + (bid >> 3); }  // XCD swizzle
  int jl = bid / tilesPerJ;
  int t0 = bid % tilesPerJ;
  int bm = t0 / tilesN, bn = t0 % tilesN;
  int jg = jBase + jl;

  const u8* Aj = A + (size_t)jl * Mm * Kk + (size_t)bm * 256 * Kk;
  const u8* Bj = B + (size_t)jl * Nn * Kk + (size_t)bn * 256 * Kk;

  int tid = threadIdx.x;
  int lane = tid & 63, wid = tid >> 6;
  int wm = wid >> 2, wn = wid & 3;

  // ---- staging source: invert slot S = wid*64 + lane ----
  {
  }
  int S = wid * 64 + lane;
  int ib_s = S >> 7;
  int s2 = S & 127;
  int lh_s = s2 >> 6;
  int s3 = s2 & 63;
  int l31_s = s3 >> 1;
  int hs = s3 & 1;
  int h_s = hs ^ ((l31_s >> 2) & 1);
  int row_s = ib_s * 32 + l31_s;
  int koff_s = lh_s * 32 + h_s * 16;
  const u8* AsrcC0 = Aj + (size_t)row_s * Kk + koff_s;
  const u8* AsrcC1 = Aj + (size_t)(128 + row_s) * Kk + koff_s;
  const u8* BsrcC0 = Bj + (size_t)row_s * Kk + koff_s;
  const u8* BsrcC1 = Bj + (size_t)(128 + row_s) * Kk + koff_s;

  // ---- read addressing ----
  int l31 = lane & 31;
  int lh = lane >> 5;
  int x16 = ((l31 >> 2) & 1) << 4;
  int loOff = lh * 1024 + l31 * 32 + x16;         // k bytes 0-15 of lane's 32
  int hiOff = lh * 1024 + l31 * 32 + (16 ^ x16);  // k bytes 16-31
  // B block base for wave wn: chunk (wn>>1), local block (wn&1)*2 + jb
  int bBlk = (wn >> 1) * 8192 + ((wn & 1) * 2) * 2048;

  int NT = Kk >> 6;
  f32x16 acc[4][2] = {};

#define STAGE4(tt_)                                                              \
  { gload16(AsrcC0 + (size_t)(tt_) * 64, &smem[((tt_) & 3) * 16384 + wid * 1024]); \
    gload16(AsrcC1 + (size_t)(tt_) * 64, &smem[((tt_) & 3) * 16384 + 8192 + wid * 1024]); \
    gload16(BsrcC0 + (size_t)(tt_) * 64, &smem[65536 + ((tt_) & 3) * 16384 + wid * 1024]); \
    gload16(BsrcC1 + (size_t)(tt_) * 64, &smem[65536 + ((tt_) & 3) * 16384 + 8192 + wid * 1024]); }

#define BAR() asm volatile("s_barrier" ::: "memory")

  STAGE4(0);
  if (NT > 1) STAGE4(1);
  if (NT > 2) STAGE4(2);
  if (NT > 2)      asm volatile("s_waitcnt vmcnt(8)" ::: "memory");
  else if (NT > 1) asm volatile("s_waitcnt vmcnt(4)" ::: "memory");
  else             asm volatile("s_waitcnt vmcnt(0)" ::: "memory");
  BAR();

#pragma unroll 1
  for (int t = 0; t < NT; ++t) {
    const u8* Ab = &smem[(t & 3) * 16384 + wm * 8192];          // wave's 128 A rows
    const u8* Bb = &smem[65536 + (t & 3) * 16384 + bBlk];       // wave's 64 B rows
    i32x8 Afr[4], Bfr[2];
#pragma unroll
    for (int ib = 0; ib < 4; ++ib) {
      u32x4 lo = *(const u32x4*)(Ab + ib * 2048 + loOff);
      u32x4 hi = *(const u32x4*)(Ab + ib * 2048 + hiOff);
      Afr[ib][0] = lo[0]; Afr[ib][1] = lo[1]; Afr[ib][2] = lo[2]; Afr[ib][3] = lo[3];
      Afr[ib][4] = hi[0]; Afr[ib][5] = hi[1]; Afr[ib][6] = hi[2]; Afr[ib][7] = hi[3];
    }
#pragma unroll
    for (int jb = 0; jb < 2; ++jb) {
      u32x4 lo = *(const u32x4*)(Bb + jb * 2048 + loOff);
      u32x4 hi = *(const u32x4*)(Bb + jb * 2048 + hiOff);
      Bfr[jb][0] = lo[0]; Bfr[jb][1] = lo[1]; Bfr[jb][2] = lo[2]; Bfr[jb][3] = lo[3];
      Bfr[jb][4] = hi[0]; Bfr[jb][5] = hi[1]; Bfr[jb][6] = hi[2]; Bfr[jb][7] = hi[3];
    }
    if (t + 3 < NT) STAGE4(t + 3);
    __builtin_amdgcn_s_setprio(1);
#pragma unroll
    for (int ib = 0; ib < 4; ++ib)
#pragma unroll
      for (int jb = 0; jb < 2; ++jb)
        acc[ib][jb] = __builtin_amdgcn_mfma_scale_f32_32x32x64_f8f6f4(
            Afr[ib], Bfr[jb], acc[ib][jb], 0, 0, 0, 127, 0, 127);
    __builtin_amdgcn_s_setprio(0);
    if (t + 1 < NT) {
      asm volatile("s_waitcnt lgkmcnt(0)" ::: "memory");
      if (t + 3 < NT)      asm volatile("s_waitcnt vmcnt(8)" ::: "memory");
      else if (t + 2 < NT) asm volatile("s_waitcnt vmcnt(4)" ::: "memory");
      else                 asm volatile("s_waitcnt vmcnt(0)" ::: "memory");
      BAR();
    }
  }
#undef STAGE4
#undef BAR

  // C/D: col=lane&31, row=(reg&3)+8*(reg>>2)+4*(lane>>5)
  int col0 = bn * 256 + wn * 64 + l31;
  int row0 = bm * 256 + wm * 128 + lh * 4;
  bf16_t* Cj = Cout + (size_t)jg * Mm * Nn;
  float bv0 = (jg == 7) ? bias[col0] : 0.f;
  float bv1 = (jg == 7) ? bias[col0 + 32] : 0.f;
#pragma unroll
  for (int ib = 0; ib < 4; ++ib) {
#pragma unroll
    for (int jb = 0; jb < 2; ++jb) {
      float bv = jb ? bv1 : bv0;
      int gc = col0 + jb * 32;
#pragma unroll
      for (int reg = 0; reg < 16; ++reg) {
        int gr = row0 + ib * 32 + (reg & 3) + 8 * (reg >> 2);
        Cj[(size_t)gr * Nn + gc] = (bf16_t)(acc[ib][jb][reg] + bv);
      }
    }
  }
}

// ---------------- 128x128-tile bf16 GEMM for the output projection ----------------
__global__ __launch_bounds__(256)
void gemm_bt_epi(const bf16_t* __restrict__ A, const bf16_t* __restrict__ B,
                 float* __restrict__ Cout, const float* __restrict__ bias,
                 const bf16_t* __restrict__ vin, int Mm, int Nn, int Kk, int tilesN)
{
  __shared__ bf16_t As[128 * 64];
  __shared__ bf16_t Bs[128 * 64];
  int bid = blockIdx.x;
  int bm = bid / tilesN, bn = bid % tilesN;
  const bf16_t* Aj = A + (size_t)bm * 128 * Kk;
  const bf16_t* Bj = B + (size_t)bn * 128 * Kk;

  int tid = threadIdx.x;
  int lane = tid & 63, wv = tid >> 6;
  int wm = wv >> 1, wn = wv & 1;

  f32x4 acc[4][4] = {};

  int srow = wv * 32 + (lane >> 3);
  int scol = (lane & 7) * 8;
  const bf16_t* Ag = Aj + (size_t)srow * Kk + scol;
  const bf16_t* Bg = Bj + (size_t)srow * Kk + scol;

  for (int kt = 0; kt < Kk; kt += 64) {
#pragma unroll
    for (int c = 0; c < 4; ++c) {
      gload16(Ag + kt + (size_t)(c * 8) * Kk, &As[(wv * 32 + c * 8) * 64]);
      gload16(Bg + kt + (size_t)(c * 8) * Kk, &Bs[(wv * 32 + c * 8) * 64]);
    }
    __syncthreads();
#pragma unroll
    for (int ks = 0; ks < 2; ++ks) {
      int ko = ks * 32 + (lane >> 4) * 8;
      bf16x8 af[4], bfr[4];
#pragma unroll
      for (int i = 0; i < 4; ++i) {
        af[i] = *(const bf16x8*)&As[(wm * 64 + i * 16 + (lane & 15)) * 64 + ko];
        bfr[i] = *(const bf16x8*)&Bs[(wn * 64 + i * 16 + (lane & 15)) * 64 + ko];
      }
#pragma unroll
      for (int i = 0; i < 4; ++i)
#pragma unroll
        for (int j2 = 0; j2 < 4; ++j2)
          acc[i][j2] = __builtin_amdgcn_mfma_f32_16x16x32_bf16(af[i], bfr[j2], acc[i][j2], 0, 0, 0);
    }
    __syncthreads();
  }

  int rowBase = bm * 128 + wm * 64 + (lane >> 4) * 4;
  int colBase = bn * 128 + wn * 64 + (lane & 15);
#pragma unroll
  for (int i = 0; i < 4; ++i) {
#pragma unroll
    for (int j2 = 0; j2 < 4; ++j2) {
      int gn = colBase + j2 * 16;
      float bv = bias[gn];
#pragma unroll
      for (int r = 0; r < 4; ++r) {
        int gm = rowBase + i * 16 + r;
        Cout[(size_t)gm * Nn + gn] = acc[i][j2][r] + bv + (float)vin[(size_t)gm * Nn + gn];
      }
    }
  }
}

// ---------------- attention over 6 kv slabs (vo bf16) ----------------
__global__ __launch_bounds__(512)
void attn_fuse(const bf16_t* __restrict__ vo, bf16_t* __restrict__ fuse)
{
  int m = blockIdx.x;
  int h = threadIdx.x >> 6;
  int lane = threadIdx.x & 63;
  const size_t slab = (size_t)M_TOK * CDIM;
  const bf16_t* base = vo + (size_t)m * CDIM + h * 128;
  float q0 = (float)base[lane], q1 = (float)base[lane + 64];
  float kv0[6], kv1[6], sc[6];
#pragma unroll
  for (int k = 0; k < 6; ++k) {
    const bf16_t* kb = base + (size_t)(k + 1) * slab;
    kv0[k] = (float)kb[lane]; kv1[k] = (float)kb[lane + 64];
    sc[k] = q0 * kv0[k] + q1 * kv1[k];
  }
#pragma unroll
  for (int k = 0; k < 6; ++k) {
#pragma unroll
    for (int off = 32; off; off >>= 1) sc[k] += __shfl_xor(sc[k], off);
    sc[k] *= 0.03125f;  // C^-0.5
  }
  float mx = sc[0];
#pragma unroll
  for (int k = 1; k < 6; ++k) mx = fmaxf(mx, sc[k]);
  float e[6], se = 0.f;
#pragma unroll
  for (int k = 0; k < 6; ++k) { e[k] = expf(sc[k] - mx); se += e[k]; }
  float inv = 1.f / se;
  float f0 = 0.f, f1 = 0.f;
#pragma unroll
  for (int k = 0; k < 6; ++k) { float w = e[k] * inv; f0 += w * kv0[k]; f1 += w * kv1[k]; }
  bf16_t* o = fuse + (size_t)m * CDIM + h * 128;
  o[lane] = (bf16_t)f0;
  o[lane + 64] = (bf16_t)f1;
}

// ---------------- cosine per row ----------------
__global__ __launch_bounds__(256)
void cos_row(const float* __restrict__ vf, const float* __restrict__ teacher, float* __restrict__ cosv)
{
  int m = blockIdx.x;
  int tid = threadIdx.x;
  float4 a = ((const float4*)(vf + (size_t)m * CDIM))[tid];
  float4 b = ((const float4*)(teacher + (size_t)m * CDIM))[tid];
  float dot = a.x * b.x + a.y * b.y + a.z * b.z + a.w * b.w;
  float na = a.x * a.x + a.y * a.y + a.z * a.z + a.w * a.w;
  float nb = b.x * b.x + b.y * b.y + b.z * b.z + b.w * b.w;
  int lane = tid & 63, wv = tid >> 6;
#pragma unroll
  for (int off = 32; off; off >>= 1) {
    dot += __shfl_xor(dot, off); na += __shfl_xor(na, off); nb += __shfl_xor(nb, off);
  }
  __shared__ float red[12];
  if (lane == 0) { red[wv] = dot; red[4 + wv] = na; red[8 + wv] = nb; }
  __syncthreads();
  if (tid == 0) {
    float d = red[0] + red[1] + red[2] + red[3];
    float x = red[4] + red[5] + red[6] + red[7];
    float y = red[8] + red[9] + red[10] + red[11];
    float den = fmaxf(sqrtf(x), 1e-8f) * fmaxf(sqrtf(y), 1e-8f);
    cosv[m] = d / den;
  }
}

__global__ __launch_bounds__(256)
void final_reduce(const float* __restrict__ cosv, float* __restrict__ out)
{
  int tid = threadIdx.x;
  float s = 0.f;
  for (int i = tid; i < M_TOK; i += 256) s += cosv[i];
  int lane = tid & 63, wv = tid >> 6;
#pragma unroll
  for (int off = 32; off; off >>= 1) s += __shfl_xor(s, off);
  __shared__ float red[4];
  if (lane == 0) red[wv] = s;
  __syncthreads();
  if (tid == 0) out[0] = 1.f - (red[0] + red[1] + red[2] + red[3]) * (1.f / M_TOK);
}

extern "C" void kernel_launch(void* const* d_in, const int* in_sizes, int n_in,
                              void* d_out, int out_size, void* d_ws, size_t ws_size,
                              hipStream_t stream)
{
  (void)in_sizes; (void)n_in; (void)out_size;
  const float* all_features = (const float*)d_in[0];
  const float* teacher = (const float*)d_in[1];
  const float* ln_gamma = (const float*)d_in[2];
  const float* ln_beta = (const float*)d_in[3];
  const float* norm_w = (const float*)d_in[4];
  const float* input_w = (const float*)d_in[5];
  const float* input_b = (const float*)d_in[6];
  const float* output_w = (const float*)d_in[7];
  const float* output_b = (const float*)d_in[8];
  float* out = (float*)d_out;
  char* ws = (char*)d_ws;

  const size_t M = M_TOK, D = DDIM, C = CDIM;
  const size_t xnB = 8 * M * D;          // 67 MB fp8 (slab7 = raw layer24)
  const size_t wbB = 8 * C * D;          // 33.5 MB fp8 (norm_w[0..6] + input_w)
  const size_t owbB = C * C * 2;         // 2 MB bf16
  const size_t voB = 8 * M * C * 2;      // 33.5 MB bf16 (slab7 = vin)
  const size_t fuseB = M * C * 2;
  const size_t vfB = M * C * 4;
  const size_t cosB = M * 4;
  const size_t fastTotal = xnB + wbB + owbB + voB + fuseB + vfB + cosB;  // ~148 MB

  if (ws_size >= fastTotal) {
    u8* xn = (u8*)ws;
    u8* wb = (u8*)(ws + xnB);
    bf16_t* owb = (bf16_t*)(ws + xnB + wbB);
    bf16_t* vo = (bf16_t*)(ws + xnB + wbB + owbB);
    bf16_t* fuse = (bf16_t*)(ws + xnB + wbB + owbB + voB);
    float* vf = (float*)(ws + xnB + wbB + owbB + voB + fuseB);
    float* cosv = (float*)(ws + xnB + wbB + owbB + voB + fuseB + vfB);

    dim3 gp((unsigned)M, 8);
    prep<<<gp, 256, 0, stream>>>(all_features, ln_gamma, ln_beta, xn,
                                 norm_w, input_w, output_w, wb, owb);
    gemm256mx<<<256, 512, 0, stream>>>(xn, wb, vo, input_b,
                                       (int)M, (int)C, (int)D, 0, 32, 4);
    attn_fuse<<<(unsigned)M, 512, 0, stream>>>(vo, fuse);
    gemm_bt_epi<<<128, 256, 0, stream>>>(fuse, owb, vf, output_b, vo + (size_t)7 * M * C,
                                         (int)M, (int)C, (int)C, 8);
    cos_row<<<(unsigned)M, 256, 0, stream>>>(vf, teacher, cosv);
    final_reduce<<<1, 256, 0, stream>>>(cosv, out);
  } else {
    // SMALL-ws fallback: loop j, reuse one xn/wb slab (fp8).
    const size_t xn1B = M * D;
    const size_t wb1B = C * D;
    u8* xn1 = (u8*)ws;
    u8* wb1 = (u8*)(ws + xn1B);
    bf16_t* owb = (bf16_t*)(ws + xn1B + wb1B);
    bf16_t* vo = (bf16_t*)(ws + xn1B + wb1B + owbB);
    bf16_t* fuse = (bf16_t*)(ws + xn1B + wb1B + owbB + voB);
    float* vf = (float*)(ws + xn1B + wb1B + owbB + voB + fuseB);
    float* cosv = (float*)(ws + xn1B + wb1B + owbB + voB + fuseB + vfB);

    cvt_bf16<<<512, 256, 0, stream>>>(output_w, owb, (long)(C * C));
    for (int j = 0; j < 8; ++j) {
      const float* wsrc = (j < 7) ? (norm_w + (size_t)j * C * D) : input_w;
      cvt_fp8<<<2048, 256, 0, stream>>>(wsrc, wb1, (long)(C * D));
      dim3 g1((unsigned)M, 1);
      ln_convert<<<g1, 256, 0, stream>>>(all_features, ln_gamma, ln_beta, xn1, j, 0);
      gemm256mx<<<32, 512, 0, stream>>>(xn1, wb1, vo, input_b,
                                        (int)M, (int)C, (int)D, j, 32, 4);
    }
    attn_fuse<<<(unsigned)M, 512, 0, stream>>>(vo, fuse);
    gemm_bt_epi<<<128, 256, 0, stream>>>(fuse, owb, vf, output_b, vo + (size_t)7 * M * C,
                                         (int)M, (int)C, (int)C, 8);
    cos_row<<<(unsigned)M, 256, 0, stream>>>(vf, teacher, cosv);
    final_reduce<<<1, 256, 0, stream>>>(cosv, out);
  }
}